// Round 6
// baseline (348.397 us; speedup 1.0000x reference)
//
#include <hip/hip_runtime.h>
#include <hip/hip_bf16.h>

// SupplyChainGNN: 3-layer GCN, N=50000, E=800000, H=64.
// Round 5: hn (normalized features) stored as packed bf16x2 -> halves the
// gather's random-row read volume (256B -> 128B per edge) and hn write traffic.
// Accumulation fp32; g and final-layer h stay fp32. CSR bucket-sort build
// unchanged from R4.
// d_ws: g 12.8MB (ebuf aliases), hfin 12.8MB, hbf 6.4MB, dinv, row_ptr,
// histT, bbase, csr_src.

#define HDIM 64
#define PB 128          // blocks in hist/bin passes
#define NPB 512         // nodes per bucket
#define NPB_SHIFT 9

// pack two fp32 -> bf16x2 dword, round-to-nearest-even
__device__ inline unsigned bfpack(float lo, float hi) {
    unsigned ul = __float_as_uint(lo), uh = __float_as_uint(hi);
    ul += 0x7fffu + ((ul >> 16) & 1u);
    uh += 0x7fffu + ((uh >> 16) & 1u);
    return (ul >> 16) | (uh & 0xffff0000u);
}

// Pass 1: histT[k*PB + p] = #edges of block p with dst in bucket k
__global__ __launch_bounds__(256) void hist_pass(const int* __restrict__ dst,
                                                 unsigned* __restrict__ histT,
                                                 int E, int NB) {
    __shared__ unsigned h[2048];
    int t = threadIdx.x, p = blockIdx.x;
    for (int k = t; k < NB; k += 256) h[k] = 0u;
    __syncthreads();
    int chunk = (E + PB - 1) / PB;
    int lo = p * chunk, hi = min(lo + chunk, E);
    for (int e = lo + t; e < hi; e += 256)
        atomicAdd(&h[dst[e] >> NPB_SHIFT], 1u);
    __syncthreads();
    for (int k = t; k < NB; k += 256) histT[k * PB + p] = h[k];
}

// Pass 2: exclusive scan of histT (bucket-major) in place; bbase[k] = bucket start.
__global__ __launch_bounds__(256) void scan_all(unsigned* __restrict__ histT,
                                                unsigned* __restrict__ bbase,
                                                int M, int NB, int E) {
    __shared__ unsigned part[256];
    int t = threadIdx.x;
    int chunk = (M + 255) / 256;
    int lo = t * chunk, hi = min(lo + chunk, M);
    unsigned s = 0;
    for (int i = lo; i < hi; i++) s += histT[i];
    part[t] = s;
    __syncthreads();
    for (int off = 1; off < 256; off <<= 1) {
        unsigned u = (t >= off) ? part[t - off] : 0u;
        __syncthreads();
        part[t] += u;
        __syncthreads();
    }
    unsigned run = part[t] - s;
    for (int i = lo; i < hi; i++) { unsigned c = histT[i]; histT[i] = run; run += c; }
    __syncthreads();
    for (int k = t; k < NB; k += 256) bbase[k] = histT[k * PB];
    if (t == 0) bbase[NB] = (unsigned)E;
}

// Pass 3: scatter (src,dst) int2 into bucket-grouped ebuf (private runs).
__global__ __launch_bounds__(256) void bin_pass(const int* __restrict__ ei,
                                                const unsigned* __restrict__ histT,
                                                int2* __restrict__ ebuf,
                                                int E, int NB) {
    __shared__ unsigned cur[2048];
    int t = threadIdx.x, p = blockIdx.x;
    for (int k = t; k < NB; k += 256) cur[k] = histT[k * PB + p];
    __syncthreads();
    int chunk = (E + PB - 1) / PB;
    int lo = p * chunk, hi = min(lo + chunk, E);
    for (int e = lo + t; e < hi; e += 256) {
        int sN = ei[e];
        int dN = ei[E + e];
        unsigned pos = atomicAdd(&cur[dN >> NPB_SHIFT], 1u);
        ebuf[pos] = make_int2(sN, dN);
    }
}

// Pass 4: one block per bucket -> row_ptr, dinv, csr_src (LDS counting sort).
__global__ __launch_bounds__(256) void csr_pass(const int2* __restrict__ ebuf,
                                                const unsigned* __restrict__ bbase,
                                                unsigned* __restrict__ row_ptr,
                                                float* __restrict__ dinv,
                                                int* __restrict__ csr_src,
                                                int N, int E, int NB) {
    __shared__ unsigned cntL[NPB];
    __shared__ unsigned sA[NPB], sB[NPB];
    int t = threadIdx.x, k = blockIdx.x;
    unsigned e0 = bbase[k], e1 = bbase[k + 1];
    int nbase = k << NPB_SHIFT;
    for (int j = t; j < NPB; j += 256) cntL[j] = 0u;
    __syncthreads();
    for (unsigned e = e0 + t; e < e1; e += 256)
        atomicAdd(&cntL[ebuf[e].y - nbase], 1u);
    __syncthreads();
    for (int j = t; j < NPB; j += 256) sA[j] = cntL[j];
    __syncthreads();
    unsigned* sp = sA; unsigned* dp = sB;
    for (int off = 1; off < NPB; off <<= 1) {
        for (int j = t; j < NPB; j += 256)
            dp[j] = sp[j] + ((j >= off) ? sp[j - off] : 0u);
        __syncthreads();
        unsigned* tmp = sp; sp = dp; dp = tmp;
    }
    for (int j = t; j < NPB; j += 256) {
        int node = nbase + j;
        if (node < N) {
            unsigned pos0 = e0 + sp[j] - cntL[j];
            row_ptr[node] = pos0;
            dinv[node] = rsqrtf((float)(cntL[j] + 1u));
            dp[j] = pos0;
        }
    }
    if (k == NB - 1 && t == 0) row_ptr[N] = (unsigned)E;
    __syncthreads();
    for (unsigned e = e0 + t; e < e1; e += 256) {
        int2 ed = ebuf[e];
        unsigned pos = atomicAdd(&dp[ed.y - nbase], 1u);
        csr_src[pos] = ed.x;
    }
}

// hn[i][2jp..2jp+1] = bf16( dinv[i] * relu(x@W+b) ); thread per feature-pair.
__global__ __launch_bounds__(256) void encoder(const float* __restrict__ x,
                                               const float* __restrict__ W,
                                               const float* __restrict__ b,
                                               const float* __restrict__ dinv,
                                               unsigned* __restrict__ hn, int N) {
    int t = blockIdx.x * 256 + threadIdx.x;
    int i = t >> 5, jp = t & 31;
    if (i >= N) return;
    int j0 = 2 * jp;
    float a0 = b[j0], a1 = b[j0 + 1];
#pragma unroll
    for (int k = 0; k < 5; k++) {
        float xv = x[i * 5 + k];
        a0 = fmaf(xv, W[k * 64 + j0], a0);
        a1 = fmaf(xv, W[k * 64 + j0 + 1], a1);
    }
    float di = dinv[i];
    a0 = di * fmaxf(a0, 0.0f);
    a1 = di * fmaxf(a1, 0.0f);
    hn[t] = bfpack(a0, a1);
}

// Wave per node, bf16x2-packed rows (128B/edge): lanes 0-31 = edge A
// (2 feats/lane), lanes 32-63 = edge B. g[i] = hn[i] + sum_src hn[s]  (fp32).
__global__ __launch_bounds__(256) void gather2(const unsigned int* __restrict__ row_ptr,
                                               const int* __restrict__ csr_src,
                                               const unsigned* __restrict__ hn,
                                               float* __restrict__ g, int N) {
    int t = blockIdx.x * 256 + threadIdx.x;
    int i = t >> 6;
    if (i >= N) return;
    int lane = t & 63;
    int half = lane >> 5;
    int fl = lane & 31;
    float2 acc = {0.f, 0.f}, acc2 = {0.f, 0.f};
    if (half == 0) {
        unsigned u = hn[(size_t)i * 32 + fl];  // self term
        acc.x = __uint_as_float(u << 16);
        acc.y = __uint_as_float(u & 0xffff0000u);
    }
    unsigned int e0 = row_ptr[i], e1 = row_ptr[i + 1];
    unsigned int ec = e1 - e0;
    unsigned int pairs = ec >> 1;
    unsigned int base = e0 + half;
    unsigned int s = 0;
    for (; s + 2 <= pairs; s += 2) {
        int s0 = csr_src[base + 2 * s];
        int s1 = csr_src[base + 2 * s + 2];
        unsigned u0 = hn[(size_t)s0 * 32 + fl];
        unsigned u1 = hn[(size_t)s1 * 32 + fl];
        acc.x += __uint_as_float(u0 << 16);
        acc.y += __uint_as_float(u0 & 0xffff0000u);
        acc2.x += __uint_as_float(u1 << 16);
        acc2.y += __uint_as_float(u1 & 0xffff0000u);
    }
    if (s < pairs) {
        unsigned u0 = hn[(size_t)csr_src[base + 2 * s] * 32 + fl];
        acc.x += __uint_as_float(u0 << 16);
        acc.y += __uint_as_float(u0 & 0xffff0000u);
    }
    if ((ec & 1u) && half == 0) {
        unsigned u0 = hn[(size_t)csr_src[e1 - 1] * 32 + fl];
        acc2.x += __uint_as_float(u0 << 16);
        acc2.y += __uint_as_float(u0 & 0xffff0000u);
    }
    acc.x += acc2.x; acc.y += acc2.y;
    acc.x += __shfl_xor(acc.x, 32, 64);
    acc.y += __shfl_xor(acc.y, 32, 64);
    if (half == 0) {
        float2* g2 = (float2*)g;
        g2[(size_t)i * 32 + fl] = acc;
    }
}

// Thread per (node, output-half). Row of g (fp32) in VGPRs; W^T in LDS.
// outMode=1: write bf16 hn_next = dinv*relu(...)  (layers 0,1)
// outMode=0: write fp32 h = relu(...)             (layer 2, feeds heads)
__global__ __launch_bounds__(256) void conv_relu(const float* __restrict__ g,
                                                 const float* __restrict__ W,
                                                 const float* __restrict__ b,
                                                 const float* __restrict__ dinv,
                                                 float* __restrict__ houtF,
                                                 unsigned* __restrict__ houtB,
                                                 int N, int outMode) {
    __shared__ float WT[64 * 68];
    int tid = threadIdx.x;
    for (int e = tid; e < 4096; e += 256) {
        int k = e >> 6, j = e & 63;
        WT[j * 68 + k] = W[e];
    }
    __syncthreads();
    int half = tid >> 7;
    int i = blockIdx.x * 128 + (tid & 127);
    if (i >= N) return;
    float4 h[16];
    const float4* g4 = (const float4*)(g + (size_t)i * 64);
#pragma unroll
    for (int q = 0; q < 16; q++) h[q] = g4[q];
    float di = dinv[i];
    float os = outMode ? di : 1.0f;
    int jb = half * 32;
#pragma unroll
    for (int j0 = 0; j0 < 32; j0 += 4) {
        float4 acc = {0.f, 0.f, 0.f, 0.f};
        const float* w0 = &WT[(jb + j0) * 68];
#pragma unroll
        for (int q = 0; q < 16; q++) {
            float4 hv = h[q];
            float4 wa = *(const float4*)(w0 + 0 * 68 + 4 * q);
            float4 wb = *(const float4*)(w0 + 1 * 68 + 4 * q);
            float4 wc = *(const float4*)(w0 + 2 * 68 + 4 * q);
            float4 wd = *(const float4*)(w0 + 3 * 68 + 4 * q);
            acc.x = fmaf(hv.x, wa.x, acc.x); acc.x = fmaf(hv.y, wa.y, acc.x);
            acc.x = fmaf(hv.z, wa.z, acc.x); acc.x = fmaf(hv.w, wa.w, acc.x);
            acc.y = fmaf(hv.x, wb.x, acc.y); acc.y = fmaf(hv.y, wb.y, acc.y);
            acc.y = fmaf(hv.z, wb.z, acc.y); acc.y = fmaf(hv.w, wb.w, acc.y);
            acc.z = fmaf(hv.x, wc.x, acc.z); acc.z = fmaf(hv.y, wc.y, acc.z);
            acc.z = fmaf(hv.z, wc.z, acc.z); acc.z = fmaf(hv.w, wc.w, acc.z);
            acc.w = fmaf(hv.x, wd.x, acc.w); acc.w = fmaf(hv.y, wd.y, acc.w);
            acc.w = fmaf(hv.z, wd.z, acc.w); acc.w = fmaf(hv.w, wd.w, acc.w);
        }
        float4 y;
        y.x = fmaxf(fmaf(di, acc.x, b[jb + j0 + 0]), 0.f) * os;
        y.y = fmaxf(fmaf(di, acc.y, b[jb + j0 + 1]), 0.f) * os;
        y.z = fmaxf(fmaf(di, acc.z, b[jb + j0 + 2]), 0.f) * os;
        y.w = fmaxf(fmaf(di, acc.w, b[jb + j0 + 3]), 0.f) * os;
        if (outMode) {
            uint2 p;
            p.x = bfpack(y.x, y.y);
            p.y = bfpack(y.z, y.w);
            *(uint2*)(houtB + (size_t)i * 32 + ((jb + j0) >> 1)) = p;
        } else {
            *(float4*)(houtF + (size_t)i * 64 + jb + j0) = y;
        }
    }
}

// Thread per (node, head). tid<128 -> demand, tid>=128 -> inventory.
__global__ __launch_bounds__(256) void heads2(const float* __restrict__ h,
                                              const float* __restrict__ W_d1, const float* __restrict__ b_d1,
                                              const float* __restrict__ W_d2, const float* __restrict__ b_d2,
                                              const float* __restrict__ W_i1, const float* __restrict__ b_i1,
                                              const float* __restrict__ W_i2, const float* __restrict__ b_i2,
                                              float* __restrict__ out, int N) {
    __shared__ float WT[2][32 * 68];
    int tid = threadIdx.x;
    for (int e = tid; e < 2048; e += 256) {
        int k = e >> 5, j = e & 31;
        WT[0][j * 68 + k] = W_d1[e];
        WT[1][j * 68 + k] = W_i1[e];
    }
    __syncthreads();
    int head = tid >> 7;
    int i = blockIdx.x * 128 + (tid & 127);
    if (i >= N) return;
    float4 hr[16];
    const float4* h4 = (const float4*)(h + (size_t)i * 64);
#pragma unroll
    for (int q = 0; q < 16; q++) hr[q] = h4[q];
    const float* W1T = WT[head];
    const float* b1 = head ? b_i1 : b_d1;
    const float* W2 = head ? W_i2 : W_d2;
    float o = head ? b_i2[0] : b_d2[0];
#pragma unroll
    for (int j0 = 0; j0 < 32; j0 += 4) {
        float4 acc = {b1[j0], b1[j0 + 1], b1[j0 + 2], b1[j0 + 3]};
        const float* w0 = &W1T[j0 * 68];
#pragma unroll
        for (int q = 0; q < 16; q++) {
            float4 hv = hr[q];
            float4 wa = *(const float4*)(w0 + 0 * 68 + 4 * q);
            float4 wb = *(const float4*)(w0 + 1 * 68 + 4 * q);
            float4 wc = *(const float4*)(w0 + 2 * 68 + 4 * q);
            float4 wd = *(const float4*)(w0 + 3 * 68 + 4 * q);
            acc.x = fmaf(hv.x, wa.x, acc.x); acc.x = fmaf(hv.y, wa.y, acc.x);
            acc.x = fmaf(hv.z, wa.z, acc.x); acc.x = fmaf(hv.w, wa.w, acc.x);
            acc.y = fmaf(hv.x, wb.x, acc.y); acc.y = fmaf(hv.y, wb.y, acc.y);
            acc.y = fmaf(hv.z, wb.z, acc.y); acc.y = fmaf(hv.w, wb.w, acc.y);
            acc.z = fmaf(hv.x, wc.x, acc.z); acc.z = fmaf(hv.y, wc.y, acc.z);
            acc.z = fmaf(hv.z, wc.z, acc.z); acc.z = fmaf(hv.w, wc.w, acc.z);
            acc.w = fmaf(hv.x, wd.x, acc.w); acc.w = fmaf(hv.y, wd.y, acc.w);
            acc.w = fmaf(hv.z, wd.z, acc.w); acc.w = fmaf(hv.w, wd.w, acc.w);
        }
        o = fmaf(fmaxf(acc.x, 0.f), W2[j0 + 0], o);
        o = fmaf(fmaxf(acc.y, 0.f), W2[j0 + 1], o);
        o = fmaf(fmaxf(acc.z, 0.f), W2[j0 + 2], o);
        o = fmaf(fmaxf(acc.w, 0.f), W2[j0 + 3], o);
    }
    out[(size_t)head * N + i] = o;
}

extern "C" void kernel_launch(void* const* d_in, const int* in_sizes, int n_in,
                              void* d_out, int out_size, void* d_ws, size_t ws_size,
                              hipStream_t stream) {
    const float* x      = (const float*)d_in[0];
    const int*   ei     = (const int*)d_in[1];
    const float* W_enc  = (const float*)d_in[2];
    const float* b_enc  = (const float*)d_in[3];
    const float* conv_W = (const float*)d_in[4];
    const float* conv_b = (const float*)d_in[5];
    const float* W_d1   = (const float*)d_in[6];
    const float* b_d1   = (const float*)d_in[7];
    const float* W_d2   = (const float*)d_in[8];
    const float* b_d2   = (const float*)d_in[9];
    const float* W_i1   = (const float*)d_in[10];
    const float* b_i1   = (const float*)d_in[11];
    const float* W_i2   = (const float*)d_in[12];
    const float* b_i2   = (const float*)d_in[13];

    const int N = in_sizes[0] / 5;
    const int E = in_sizes[1] / 2;
    const int NB = (N + NPB - 1) >> NPB_SHIFT;

    float* g    = (float*)d_ws;                         // [N*64] fp32 (ebuf aliases)
    float* hfin = g + (size_t)N * HDIM;                 // [N*64] fp32 (layer-2 out)
    unsigned* hbf = (unsigned*)(hfin + (size_t)N * HDIM); // [N*32] bf16x2
    float* dinv = (float*)(hbf + (size_t)N * 32);
    unsigned int* row_ptr = (unsigned int*)(dinv + N);  // [N+1]
    unsigned int* histT   = row_ptr + N + 1;            // [NB*PB]
    unsigned int* bbase   = histT + (size_t)NB * PB;    // [NB+1]
    int* csr_src          = (int*)(bbase + NB + 1);     // [E]
    int2* ebuf            = (int2*)g;                   // [E] (dead before layer 0)
    float* out = (float*)d_out;

    const int nwBlocks = (N + 3) / 4;        // wave per node
    const int tnBlocks = (N + 127) / 128;    // 2 threads per node

    // CSR build: bucket sort, no global atomics
    hist_pass<<<PB, 256, 0, stream>>>(ei + E, histT, E, NB);
    scan_all<<<1, 256, 0, stream>>>(histT, bbase, NB * PB, NB, E);
    bin_pass<<<PB, 256, 0, stream>>>(ei, histT, ebuf, E, NB);
    csr_pass<<<NB, 256, 0, stream>>>(ebuf, bbase, row_ptr, dinv, csr_src, N, E, NB);

    // encoder -> hn0 (bf16)
    encoder<<<(N * 32 + 255) / 256, 256, 0, stream>>>(x, W_enc, b_enc, dinv, hbf, N);

    // 3 GCN layers
    for (int l = 0; l < 3; l++) {
        gather2<<<nwBlocks, 256, 0, stream>>>(row_ptr, csr_src, hbf, g, N);
        conv_relu<<<tnBlocks, 256, 0, stream>>>(g, conv_W + l * HDIM * HDIM,
                                                conv_b + l * HDIM, dinv, hfin, hbf, N,
                                                (l < 2) ? 1 : 0);
    }

    // heads
    heads2<<<tnBlocks, 256, 0, stream>>>(hfin, W_d1, b_d1, W_d2, b_d2,
                                         W_i1, b_i1, W_i2, b_i2, out, N);
}

// Round 7
// 306.378 us; speedup vs baseline: 1.1371x; 1.1371x over previous
//
#include <hip/hip_runtime.h>
#include <hip/hip_bf16.h>

// SupplyChainGNN: 3-layer GCN, N=50000, E=800000, H=64.
// Round 6: (a) two-level parallel scan replaces the single-block scan_all
// (was ~35us serial over 12.5k entries); (b) csr_pass occupancy doubled
// (NPB 512->256, 196 blocks); (c) gather halves own their edge sub-lists
// with 4-way unroll (8 rows in flight/wave). hn stays packed bf16x2.

#define HDIM 64
#define PB 128          // blocks in hist/bin passes
#define NPB 256         // nodes per bucket
#define NPB_SHIFT 8

// pack two fp32 -> bf16x2 dword, round-to-nearest-even
__device__ inline unsigned bfpack(float lo, float hi) {
    unsigned ul = __float_as_uint(lo), uh = __float_as_uint(hi);
    ul += 0x7fffu + ((ul >> 16) & 1u);
    uh += 0x7fffu + ((uh >> 16) & 1u);
    return (ul >> 16) | (uh & 0xffff0000u);
}

// Pass 1: histT[k*PB + p] = #edges of block p with dst in bucket k
__global__ __launch_bounds__(256) void hist_pass(const int* __restrict__ dst,
                                                 unsigned* __restrict__ histT,
                                                 int E, int NB) {
    __shared__ unsigned h[2048];
    int t = threadIdx.x, p = blockIdx.x;
    for (int k = t; k < NB; k += 256) h[k] = 0u;
    __syncthreads();
    int chunk = (E + PB - 1) / PB;
    int lo = p * chunk, hi = min(lo + chunk, E);
    for (int e = lo + t; e < hi; e += 256)
        atomicAdd(&h[dst[e] >> NPB_SHIFT], 1u);
    __syncthreads();
    for (int k = t; k < NB; k += 256) histT[k * PB + p] = h[k];
}

// Pass 2a: per-bucket exclusive scan of its PB per-block counts (in place);
// bucket total -> btot[k].
__global__ __launch_bounds__(128) void scan_bucket(unsigned* __restrict__ histT,
                                                   unsigned* __restrict__ btot) {
    __shared__ unsigned s[PB];
    int t = threadIdx.x, k = blockIdx.x;
    unsigned v = histT[k * PB + t];
    s[t] = v;
    __syncthreads();
#pragma unroll
    for (int off = 1; off < PB; off <<= 1) {
        unsigned u = (t >= off) ? s[t - off] : 0u;
        __syncthreads();
        s[t] += u;
        __syncthreads();
    }
    histT[k * PB + t] = s[t] - v;          // exclusive within bucket
    if (t == PB - 1) btot[k] = s[t];       // bucket total
}

// Pass 2b: single-block exclusive scan of the NB bucket totals -> bbase.
__global__ __launch_bounds__(256) void scan_btot(const unsigned* __restrict__ btot,
                                                 unsigned* __restrict__ bbase,
                                                 int NB, int E) {
    __shared__ unsigned s[256];
    int t = threadIdx.x;
    unsigned v = (t < NB) ? btot[t] : 0u;
    s[t] = v;
    __syncthreads();
#pragma unroll
    for (int off = 1; off < 256; off <<= 1) {
        unsigned u = (t >= off) ? s[t - off] : 0u;
        __syncthreads();
        s[t] += u;
        __syncthreads();
    }
    if (t < NB) bbase[t] = s[t] - v;
    if (t == 0) bbase[NB] = (unsigned)E;
}

// Pass 3: scatter (src,dst) int2 into bucket-grouped ebuf (private runs).
__global__ __launch_bounds__(256) void bin_pass(const int* __restrict__ ei,
                                                const unsigned* __restrict__ histT,
                                                const unsigned* __restrict__ bbase,
                                                int2* __restrict__ ebuf,
                                                int E, int NB) {
    __shared__ unsigned cur[2048];
    int t = threadIdx.x, p = blockIdx.x;
    for (int k = t; k < NB; k += 256) cur[k] = histT[k * PB + p] + bbase[k];
    __syncthreads();
    int chunk = (E + PB - 1) / PB;
    int lo = p * chunk, hi = min(lo + chunk, E);
    for (int e = lo + t; e < hi; e += 256) {
        int sN = ei[e];
        int dN = ei[E + e];
        unsigned pos = atomicAdd(&cur[dN >> NPB_SHIFT], 1u);
        ebuf[pos] = make_int2(sN, dN);
    }
}

// Pass 4: one block per bucket (256 nodes) -> row_ptr, dinv, csr_src.
__global__ __launch_bounds__(256) void csr_pass(const int2* __restrict__ ebuf,
                                                const unsigned* __restrict__ bbase,
                                                unsigned* __restrict__ row_ptr,
                                                float* __restrict__ dinv,
                                                int* __restrict__ csr_src,
                                                int N, int E, int NB) {
    __shared__ unsigned cntL[NPB];
    __shared__ unsigned sc[NPB];
    __shared__ unsigned cur[NPB];
    int t = threadIdx.x, k = blockIdx.x;
    unsigned e0 = bbase[k], e1 = bbase[k + 1];
    int nbase = k << NPB_SHIFT;
    cntL[t] = 0u;
    __syncthreads();
    for (unsigned e = e0 + t; e < e1; e += 256)
        atomicAdd(&cntL[ebuf[e].y - nbase], 1u);
    __syncthreads();
    unsigned v = cntL[t];
    sc[t] = v;
    __syncthreads();
#pragma unroll
    for (int off = 1; off < NPB; off <<= 1) {
        unsigned u = (t >= off) ? sc[t - off] : 0u;
        __syncthreads();
        sc[t] += u;
        __syncthreads();
    }
    unsigned pos0 = e0 + sc[t] - v;   // exclusive
    cur[t] = pos0;
    int node = nbase + t;
    if (node < N) {
        row_ptr[node] = pos0;
        dinv[node] = rsqrtf((float)(v + 1u));
    }
    if (k == NB - 1 && t == 0) row_ptr[N] = (unsigned)E;
    __syncthreads();
    for (unsigned e = e0 + t; e < e1; e += 256) {
        int2 ed = ebuf[e];
        unsigned pos = atomicAdd(&cur[ed.y - nbase], 1u);
        csr_src[pos] = ed.x;
    }
}

// hn[i][2jp..2jp+1] = bf16( dinv[i] * relu(x@W+b) ); thread per feature-pair.
__global__ __launch_bounds__(256) void encoder(const float* __restrict__ x,
                                               const float* __restrict__ W,
                                               const float* __restrict__ b,
                                               const float* __restrict__ dinv,
                                               unsigned* __restrict__ hn, int N) {
    int t = blockIdx.x * 256 + threadIdx.x;
    int i = t >> 5, jp = t & 31;
    if (i >= N) return;
    int j0 = 2 * jp;
    float a0 = b[j0], a1 = b[j0 + 1];
#pragma unroll
    for (int k = 0; k < 5; k++) {
        float xv = x[i * 5 + k];
        a0 = fmaf(xv, W[k * 64 + j0], a0);
        a1 = fmaf(xv, W[k * 64 + j0 + 1], a1);
    }
    float di = dinv[i];
    a0 = di * fmaxf(a0, 0.0f);
    a1 = di * fmaxf(a1, 0.0f);
    hn[t] = bfpack(a0, a1);
}

__device__ inline float2 bfunpack(unsigned u) {
    float2 r;
    r.x = __uint_as_float(u << 16);
    r.y = __uint_as_float(u & 0xffff0000u);
    return r;
}

// Wave per node, bf16x2 rows (128B/edge). Each 32-lane half owns its edge
// sub-list (half0: even offsets, ceil(ec/2); half1: odd, floor), 4-way unroll
// -> up to 8 independent row loads in flight per wave.
__global__ __launch_bounds__(256) void gather2(const unsigned int* __restrict__ row_ptr,
                                               const int* __restrict__ csr_src,
                                               const unsigned* __restrict__ hn,
                                               float* __restrict__ g, int N) {
    int t = blockIdx.x * 256 + threadIdx.x;
    int i = t >> 6;
    if (i >= N) return;
    int lane = t & 63;
    int half = lane >> 5;
    int fl = lane & 31;
    float2 a0 = {0.f, 0.f}, a1 = {0.f, 0.f}, a2 = {0.f, 0.f}, a3 = {0.f, 0.f};
    if (half == 0) a0 = bfunpack(hn[(size_t)i * 32 + fl]);  // self term
    unsigned e0 = row_ptr[i];
    unsigned ec = row_ptr[i + 1] - e0;
    unsigned cnt = (ec + 1u - (unsigned)half) >> 1;  // edges this half owns
    const int* idx = csr_src + e0 + half;
    unsigned u = 0;
    for (; u + 4 <= cnt; u += 4) {
        int s0 = idx[2 * u];
        int s1 = idx[2 * u + 2];
        int s2 = idx[2 * u + 4];
        int s3 = idx[2 * u + 6];
        unsigned v0 = hn[(size_t)s0 * 32 + fl];
        unsigned v1 = hn[(size_t)s1 * 32 + fl];
        unsigned v2 = hn[(size_t)s2 * 32 + fl];
        unsigned v3 = hn[(size_t)s3 * 32 + fl];
        float2 f0 = bfunpack(v0), f1 = bfunpack(v1), f2 = bfunpack(v2), f3 = bfunpack(v3);
        a0.x += f0.x; a0.y += f0.y;
        a1.x += f1.x; a1.y += f1.y;
        a2.x += f2.x; a2.y += f2.y;
        a3.x += f3.x; a3.y += f3.y;
    }
    for (; u < cnt; u++) {
        float2 f0 = bfunpack(hn[(size_t)idx[2 * u] * 32 + fl]);
        a0.x += f0.x; a0.y += f0.y;
    }
    a0.x += a1.x; a0.y += a1.y;
    a2.x += a3.x; a2.y += a3.y;
    a0.x += a2.x; a0.y += a2.y;
    a0.x += __shfl_xor(a0.x, 32, 64);
    a0.y += __shfl_xor(a0.y, 32, 64);
    if (half == 0) {
        float2* g2 = (float2*)g;
        g2[(size_t)i * 32 + fl] = a0;
    }
}

// Thread per (node, output-half). Row of g (fp32) in VGPRs; W^T in LDS.
// outMode=1: write bf16 hn_next = dinv*relu(...)  (layers 0,1)
// outMode=0: write fp32 h = relu(...)             (layer 2, feeds heads)
__global__ __launch_bounds__(256) void conv_relu(const float* __restrict__ g,
                                                 const float* __restrict__ W,
                                                 const float* __restrict__ b,
                                                 const float* __restrict__ dinv,
                                                 float* __restrict__ houtF,
                                                 unsigned* __restrict__ houtB,
                                                 int N, int outMode) {
    __shared__ float WT[64 * 68];
    int tid = threadIdx.x;
    for (int e = tid; e < 4096; e += 256) {
        int k = e >> 6, j = e & 63;
        WT[j * 68 + k] = W[e];
    }
    __syncthreads();
    int half = tid >> 7;
    int i = blockIdx.x * 128 + (tid & 127);
    if (i >= N) return;
    float4 h[16];
    const float4* g4 = (const float4*)(g + (size_t)i * 64);
#pragma unroll
    for (int q = 0; q < 16; q++) h[q] = g4[q];
    float di = dinv[i];
    float os = outMode ? di : 1.0f;
    int jb = half * 32;
#pragma unroll
    for (int j0 = 0; j0 < 32; j0 += 4) {
        float4 acc = {0.f, 0.f, 0.f, 0.f};
        const float* w0 = &WT[(jb + j0) * 68];
#pragma unroll
        for (int q = 0; q < 16; q++) {
            float4 hv = h[q];
            float4 wa = *(const float4*)(w0 + 0 * 68 + 4 * q);
            float4 wb = *(const float4*)(w0 + 1 * 68 + 4 * q);
            float4 wc = *(const float4*)(w0 + 2 * 68 + 4 * q);
            float4 wd = *(const float4*)(w0 + 3 * 68 + 4 * q);
            acc.x = fmaf(hv.x, wa.x, acc.x); acc.x = fmaf(hv.y, wa.y, acc.x);
            acc.x = fmaf(hv.z, wa.z, acc.x); acc.x = fmaf(hv.w, wa.w, acc.x);
            acc.y = fmaf(hv.x, wb.x, acc.y); acc.y = fmaf(hv.y, wb.y, acc.y);
            acc.y = fmaf(hv.z, wb.z, acc.y); acc.y = fmaf(hv.w, wb.w, acc.y);
            acc.z = fmaf(hv.x, wc.x, acc.z); acc.z = fmaf(hv.y, wc.y, acc.z);
            acc.z = fmaf(hv.z, wc.z, acc.z); acc.z = fmaf(hv.w, wc.w, acc.z);
            acc.w = fmaf(hv.x, wd.x, acc.w); acc.w = fmaf(hv.y, wd.y, acc.w);
            acc.w = fmaf(hv.z, wd.z, acc.w); acc.w = fmaf(hv.w, wd.w, acc.w);
        }
        float4 y;
        y.x = fmaxf(fmaf(di, acc.x, b[jb + j0 + 0]), 0.f) * os;
        y.y = fmaxf(fmaf(di, acc.y, b[jb + j0 + 1]), 0.f) * os;
        y.z = fmaxf(fmaf(di, acc.z, b[jb + j0 + 2]), 0.f) * os;
        y.w = fmaxf(fmaf(di, acc.w, b[jb + j0 + 3]), 0.f) * os;
        if (outMode) {
            uint2 p;
            p.x = bfpack(y.x, y.y);
            p.y = bfpack(y.z, y.w);
            *(uint2*)(houtB + (size_t)i * 32 + ((jb + j0) >> 1)) = p;
        } else {
            *(float4*)(houtF + (size_t)i * 64 + jb + j0) = y;
        }
    }
}

// Thread per (node, head). tid<128 -> demand, tid>=128 -> inventory.
__global__ __launch_bounds__(256) void heads2(const float* __restrict__ h,
                                              const float* __restrict__ W_d1, const float* __restrict__ b_d1,
                                              const float* __restrict__ W_d2, const float* __restrict__ b_d2,
                                              const float* __restrict__ W_i1, const float* __restrict__ b_i1,
                                              const float* __restrict__ W_i2, const float* __restrict__ b_i2,
                                              float* __restrict__ out, int N) {
    __shared__ float WT[2][32 * 68];
    int tid = threadIdx.x;
    for (int e = tid; e < 2048; e += 256) {
        int k = e >> 5, j = e & 31;
        WT[0][j * 68 + k] = W_d1[e];
        WT[1][j * 68 + k] = W_i1[e];
    }
    __syncthreads();
    int head = tid >> 7;
    int i = blockIdx.x * 128 + (tid & 127);
    if (i >= N) return;
    float4 hr[16];
    const float4* h4 = (const float4*)(h + (size_t)i * 64);
#pragma unroll
    for (int q = 0; q < 16; q++) hr[q] = h4[q];
    const float* W1T = WT[head];
    const float* b1 = head ? b_i1 : b_d1;
    const float* W2 = head ? W_i2 : W_d2;
    float o = head ? b_i2[0] : b_d2[0];
#pragma unroll
    for (int j0 = 0; j0 < 32; j0 += 4) {
        float4 acc = {b1[j0], b1[j0 + 1], b1[j0 + 2], b1[j0 + 3]};
        const float* w0 = &W1T[j0 * 68];
#pragma unroll
        for (int q = 0; q < 16; q++) {
            float4 hv = hr[q];
            float4 wa = *(const float4*)(w0 + 0 * 68 + 4 * q);
            float4 wb = *(const float4*)(w0 + 1 * 68 + 4 * q);
            float4 wc = *(const float4*)(w0 + 2 * 68 + 4 * q);
            float4 wd = *(const float4*)(w0 + 3 * 68 + 4 * q);
            acc.x = fmaf(hv.x, wa.x, acc.x); acc.x = fmaf(hv.y, wa.y, acc.x);
            acc.x = fmaf(hv.z, wa.z, acc.x); acc.x = fmaf(hv.w, wa.w, acc.x);
            acc.y = fmaf(hv.x, wb.x, acc.y); acc.y = fmaf(hv.y, wb.y, acc.y);
            acc.y = fmaf(hv.z, wb.z, acc.y); acc.y = fmaf(hv.w, wb.w, acc.y);
            acc.z = fmaf(hv.x, wc.x, acc.z); acc.z = fmaf(hv.y, wc.y, acc.z);
            acc.z = fmaf(hv.z, wc.z, acc.z); acc.z = fmaf(hv.w, wc.w, acc.z);
            acc.w = fmaf(hv.x, wd.x, acc.w); acc.w = fmaf(hv.y, wd.y, acc.w);
            acc.w = fmaf(hv.z, wd.z, acc.w); acc.w = fmaf(hv.w, wd.w, acc.w);
        }
        o = fmaf(fmaxf(acc.x, 0.f), W2[j0 + 0], o);
        o = fmaf(fmaxf(acc.y, 0.f), W2[j0 + 1], o);
        o = fmaf(fmaxf(acc.z, 0.f), W2[j0 + 2], o);
        o = fmaf(fmaxf(acc.w, 0.f), W2[j0 + 3], o);
    }
    out[(size_t)head * N + i] = o;
}

extern "C" void kernel_launch(void* const* d_in, const int* in_sizes, int n_in,
                              void* d_out, int out_size, void* d_ws, size_t ws_size,
                              hipStream_t stream) {
    const float* x      = (const float*)d_in[0];
    const int*   ei     = (const int*)d_in[1];
    const float* W_enc  = (const float*)d_in[2];
    const float* b_enc  = (const float*)d_in[3];
    const float* conv_W = (const float*)d_in[4];
    const float* conv_b = (const float*)d_in[5];
    const float* W_d1   = (const float*)d_in[6];
    const float* b_d1   = (const float*)d_in[7];
    const float* W_d2   = (const float*)d_in[8];
    const float* b_d2   = (const float*)d_in[9];
    const float* W_i1   = (const float*)d_in[10];
    const float* b_i1   = (const float*)d_in[11];
    const float* W_i2   = (const float*)d_in[12];
    const float* b_i2   = (const float*)d_in[13];

    const int N = in_sizes[0] / 5;
    const int E = in_sizes[1] / 2;
    const int NB = (N + NPB - 1) >> NPB_SHIFT;   // 196 buckets

    float* g    = (float*)d_ws;                           // [N*64] fp32 (ebuf aliases)
    float* hfin = g + (size_t)N * HDIM;                   // [N*64] fp32
    unsigned* hbf = (unsigned*)(hfin + (size_t)N * HDIM); // [N*32] bf16x2
    float* dinv = (float*)(hbf + (size_t)N * 32);
    unsigned int* row_ptr = (unsigned int*)(dinv + N);    // [N+1]
    unsigned int* histT   = row_ptr + N + 1;              // [NB*PB]
    unsigned int* btot    = histT + (size_t)NB * PB;      // [NB]
    unsigned int* bbase   = btot + NB;                    // [NB+1]
    int* csr_src          = (int*)(bbase + NB + 1);       // [E]
    int2* ebuf            = (int2*)g;                     // [E] (dead before layer 0)
    float* out = (float*)d_out;

    const int nwBlocks = (N + 3) / 4;        // wave per node
    const int tnBlocks = (N + 127) / 128;    // 2 threads per node

    // CSR build: bucket sort, no global atomics, fully parallel scans
    hist_pass<<<PB, 256, 0, stream>>>(ei + E, histT, E, NB);
    scan_bucket<<<NB, 128, 0, stream>>>(histT, btot);
    scan_btot<<<1, 256, 0, stream>>>(btot, bbase, NB, E);
    bin_pass<<<PB, 256, 0, stream>>>(ei, histT, bbase, ebuf, E, NB);
    csr_pass<<<NB, 256, 0, stream>>>(ebuf, bbase, row_ptr, dinv, csr_src, N, E, NB);

    // encoder -> hn0 (bf16)
    encoder<<<(N * 32 + 255) / 256, 256, 0, stream>>>(x, W_enc, b_enc, dinv, hbf, N);

    // 3 GCN layers
    for (int l = 0; l < 3; l++) {
        gather2<<<nwBlocks, 256, 0, stream>>>(row_ptr, csr_src, hbf, g, N);
        conv_relu<<<tnBlocks, 256, 0, stream>>>(g, conv_W + l * HDIM * HDIM,
                                                conv_b + l * HDIM, dinv, hfin, hbf, N,
                                                (l < 2) ? 1 : 0);
    }

    // heads
    heads2<<<tnBlocks, 256, 0, stream>>>(hfin, W_d1, b_d1, W_d2, b_d2,
                                         W_i1, b_i1, W_i2, b_i2, out, N);
}

// Round 8
// 292.698 us; speedup vs baseline: 1.1903x; 1.0467x over previous
//
#include <hip/hip_runtime.h>
#include <hip/hip_bf16.h>

// SupplyChainGNN: 3-layer GCN, N=50000, E=800000, H=64.
// Round 7: (a) gather restructured to half-wave (32 lanes) per node --
// contiguous edge list, no cross-half shuffle, 8-way unroll; (b) ebuf packed
// to u32 ((dst_local<<16)|src, valid for N<=65536, NPB=256) halving bin/csr
// edge-buffer traffic. hn stays packed bf16x2.

#define HDIM 64
#define PB 128          // blocks in hist/bin passes
#define NPB 256         // nodes per bucket
#define NPB_SHIFT 8

// pack two fp32 -> bf16x2 dword, round-to-nearest-even
__device__ inline unsigned bfpack(float lo, float hi) {
    unsigned ul = __float_as_uint(lo), uh = __float_as_uint(hi);
    ul += 0x7fffu + ((ul >> 16) & 1u);
    uh += 0x7fffu + ((uh >> 16) & 1u);
    return (ul >> 16) | (uh & 0xffff0000u);
}

__device__ inline float2 bfunpack(unsigned u) {
    float2 r;
    r.x = __uint_as_float(u << 16);
    r.y = __uint_as_float(u & 0xffff0000u);
    return r;
}

// Pass 1: histT[k*PB + p] = #edges of block p with dst in bucket k
__global__ __launch_bounds__(256) void hist_pass(const int* __restrict__ dst,
                                                 unsigned* __restrict__ histT,
                                                 int E, int NB) {
    __shared__ unsigned h[2048];
    int t = threadIdx.x, p = blockIdx.x;
    for (int k = t; k < NB; k += 256) h[k] = 0u;
    __syncthreads();
    int chunk = (E + PB - 1) / PB;
    int lo = p * chunk, hi = min(lo + chunk, E);
    for (int e = lo + t; e < hi; e += 256)
        atomicAdd(&h[dst[e] >> NPB_SHIFT], 1u);
    __syncthreads();
    for (int k = t; k < NB; k += 256) histT[k * PB + p] = h[k];
}

// Pass 2a: per-bucket exclusive scan of its PB per-block counts (in place);
// bucket total -> btot[k].
__global__ __launch_bounds__(128) void scan_bucket(unsigned* __restrict__ histT,
                                                   unsigned* __restrict__ btot) {
    __shared__ unsigned s[PB];
    int t = threadIdx.x, k = blockIdx.x;
    unsigned v = histT[k * PB + t];
    s[t] = v;
    __syncthreads();
#pragma unroll
    for (int off = 1; off < PB; off <<= 1) {
        unsigned u = (t >= off) ? s[t - off] : 0u;
        __syncthreads();
        s[t] += u;
        __syncthreads();
    }
    histT[k * PB + t] = s[t] - v;          // exclusive within bucket
    if (t == PB - 1) btot[k] = s[t];       // bucket total
}

// Pass 2b: single-block exclusive scan of the NB bucket totals -> bbase.
__global__ __launch_bounds__(256) void scan_btot(const unsigned* __restrict__ btot,
                                                 unsigned* __restrict__ bbase,
                                                 int NB, int E) {
    __shared__ unsigned s[256];
    int t = threadIdx.x;
    unsigned v = (t < NB) ? btot[t] : 0u;
    s[t] = v;
    __syncthreads();
#pragma unroll
    for (int off = 1; off < 256; off <<= 1) {
        unsigned u = (t >= off) ? s[t - off] : 0u;
        __syncthreads();
        s[t] += u;
        __syncthreads();
    }
    if (t < NB) bbase[t] = s[t] - v;
    if (t == 0) bbase[NB] = (unsigned)E;
}

// Pass 3: scatter packed (dst_local<<16)|src into bucket-grouped ebuf.
__global__ __launch_bounds__(256) void bin_pass(const int* __restrict__ ei,
                                                const unsigned* __restrict__ histT,
                                                const unsigned* __restrict__ bbase,
                                                unsigned* __restrict__ ebuf,
                                                int E, int NB) {
    __shared__ unsigned cur[2048];
    int t = threadIdx.x, p = blockIdx.x;
    for (int k = t; k < NB; k += 256) cur[k] = histT[k * PB + p] + bbase[k];
    __syncthreads();
    int chunk = (E + PB - 1) / PB;
    int lo = p * chunk, hi = min(lo + chunk, E);
    for (int e = lo + t; e < hi; e += 256) {
        unsigned sN = (unsigned)ei[e];
        unsigned dN = (unsigned)ei[E + e];
        unsigned pos = atomicAdd(&cur[dN >> NPB_SHIFT], 1u);
        ebuf[pos] = ((dN & (NPB - 1u)) << 16) | sN;
    }
}

// Pass 4: one block per bucket (256 nodes) -> row_ptr, dinv, csr_src.
__global__ __launch_bounds__(256) void csr_pass(const unsigned* __restrict__ ebuf,
                                                const unsigned* __restrict__ bbase,
                                                unsigned* __restrict__ row_ptr,
                                                float* __restrict__ dinv,
                                                int* __restrict__ csr_src,
                                                int N, int E, int NB) {
    __shared__ unsigned cntL[NPB];
    __shared__ unsigned sc[NPB];
    __shared__ unsigned cur[NPB];
    int t = threadIdx.x, k = blockIdx.x;
    unsigned e0 = bbase[k], e1 = bbase[k + 1];
    int nbase = k << NPB_SHIFT;
    cntL[t] = 0u;
    __syncthreads();
    for (unsigned e = e0 + t; e < e1; e += 256)
        atomicAdd(&cntL[ebuf[e] >> 16], 1u);
    __syncthreads();
    unsigned v = cntL[t];
    sc[t] = v;
    __syncthreads();
#pragma unroll
    for (int off = 1; off < NPB; off <<= 1) {
        unsigned u = (t >= off) ? sc[t - off] : 0u;
        __syncthreads();
        sc[t] += u;
        __syncthreads();
    }
    unsigned pos0 = e0 + sc[t] - v;   // exclusive
    cur[t] = pos0;
    int node = nbase + t;
    if (node < N) {
        row_ptr[node] = pos0;
        dinv[node] = rsqrtf((float)(v + 1u));
    }
    if (k == NB - 1 && t == 0) row_ptr[N] = (unsigned)E;
    __syncthreads();
    for (unsigned e = e0 + t; e < e1; e += 256) {
        unsigned ed = ebuf[e];
        unsigned pos = atomicAdd(&cur[ed >> 16], 1u);
        csr_src[pos] = (int)(ed & 0xffffu);
    }
}

// hn[i][2jp..2jp+1] = bf16( dinv[i] * relu(x@W+b) ); thread per feature-pair.
__global__ __launch_bounds__(256) void encoder(const float* __restrict__ x,
                                               const float* __restrict__ W,
                                               const float* __restrict__ b,
                                               const float* __restrict__ dinv,
                                               unsigned* __restrict__ hn, int N) {
    int t = blockIdx.x * 256 + threadIdx.x;
    int i = t >> 5, jp = t & 31;
    if (i >= N) return;
    int j0 = 2 * jp;
    float a0 = b[j0], a1 = b[j0 + 1];
#pragma unroll
    for (int k = 0; k < 5; k++) {
        float xv = x[i * 5 + k];
        a0 = fmaf(xv, W[k * 64 + j0], a0);
        a1 = fmaf(xv, W[k * 64 + j0 + 1], a1);
    }
    float di = dinv[i];
    a0 = di * fmaxf(a0, 0.0f);
    a1 = di * fmaxf(a1, 0.0f);
    hn[t] = bfpack(a0, a1);
}

// Half-wave (32 lanes) per node: contiguous edge list, 8-way unroll,
// no cross-half reduce. g[i] = hn[i] + sum_src hn[s]  (fp32 accum).
__global__ __launch_bounds__(256) void gather3(const unsigned int* __restrict__ row_ptr,
                                               const int* __restrict__ csr_src,
                                               const unsigned* __restrict__ hn,
                                               float* __restrict__ g, int N) {
    int t = blockIdx.x * 256 + threadIdx.x;
    int i = t >> 5;
    if (i >= N) return;
    int fl = t & 31;
    float2 a0 = bfunpack(hn[(size_t)i * 32 + fl]);  // self term
    float2 a1 = {0.f, 0.f}, a2 = {0.f, 0.f}, a3 = {0.f, 0.f};
    float2 a4 = {0.f, 0.f}, a5 = {0.f, 0.f}, a6 = {0.f, 0.f}, a7 = {0.f, 0.f};
    unsigned e0 = row_ptr[i];
    unsigned cnt = row_ptr[i + 1] - e0;
    const int* idx = csr_src + e0;
    unsigned u = 0;
    for (; u + 8 <= cnt; u += 8) {
        int s0 = idx[u + 0], s1 = idx[u + 1], s2 = idx[u + 2], s3 = idx[u + 3];
        int s4 = idx[u + 4], s5 = idx[u + 5], s6 = idx[u + 6], s7 = idx[u + 7];
        unsigned v0 = hn[(size_t)s0 * 32 + fl];
        unsigned v1 = hn[(size_t)s1 * 32 + fl];
        unsigned v2 = hn[(size_t)s2 * 32 + fl];
        unsigned v3 = hn[(size_t)s3 * 32 + fl];
        unsigned v4 = hn[(size_t)s4 * 32 + fl];
        unsigned v5 = hn[(size_t)s5 * 32 + fl];
        unsigned v6 = hn[(size_t)s6 * 32 + fl];
        unsigned v7 = hn[(size_t)s7 * 32 + fl];
        float2 f0 = bfunpack(v0), f1 = bfunpack(v1), f2 = bfunpack(v2), f3 = bfunpack(v3);
        float2 f4 = bfunpack(v4), f5 = bfunpack(v5), f6 = bfunpack(v6), f7 = bfunpack(v7);
        a0.x += f0.x; a0.y += f0.y;  a1.x += f1.x; a1.y += f1.y;
        a2.x += f2.x; a2.y += f2.y;  a3.x += f3.x; a3.y += f3.y;
        a4.x += f4.x; a4.y += f4.y;  a5.x += f5.x; a5.y += f5.y;
        a6.x += f6.x; a6.y += f6.y;  a7.x += f7.x; a7.y += f7.y;
    }
    for (; u < cnt; u++) {
        float2 f = bfunpack(hn[(size_t)idx[u] * 32 + fl]);
        a0.x += f.x; a0.y += f.y;
    }
    a0.x += a1.x; a0.y += a1.y;  a2.x += a3.x; a2.y += a3.y;
    a4.x += a5.x; a4.y += a5.y;  a6.x += a7.x; a6.y += a7.y;
    a0.x += a2.x; a0.y += a2.y;  a4.x += a6.x; a4.y += a6.y;
    a0.x += a4.x; a0.y += a4.y;
    float2* g2 = (float2*)g;
    g2[(size_t)i * 32 + fl] = a0;
}

// Thread per (node, output-half). Row of g (fp32) in VGPRs; W^T in LDS.
// outMode=1: write bf16 hn_next = dinv*relu(...)  (layers 0,1)
// outMode=0: write fp32 h = relu(...)             (layer 2, feeds heads)
__global__ __launch_bounds__(256) void conv_relu(const float* __restrict__ g,
                                                 const float* __restrict__ W,
                                                 const float* __restrict__ b,
                                                 const float* __restrict__ dinv,
                                                 float* __restrict__ houtF,
                                                 unsigned* __restrict__ houtB,
                                                 int N, int outMode) {
    __shared__ float WT[64 * 68];
    int tid = threadIdx.x;
    for (int e = tid; e < 4096; e += 256) {
        int k = e >> 6, j = e & 63;
        WT[j * 68 + k] = W[e];
    }
    __syncthreads();
    int half = tid >> 7;
    int i = blockIdx.x * 128 + (tid & 127);
    if (i >= N) return;
    float4 h[16];
    const float4* g4 = (const float4*)(g + (size_t)i * 64);
#pragma unroll
    for (int q = 0; q < 16; q++) h[q] = g4[q];
    float di = dinv[i];
    float os = outMode ? di : 1.0f;
    int jb = half * 32;
#pragma unroll
    for (int j0 = 0; j0 < 32; j0 += 4) {
        float4 acc = {0.f, 0.f, 0.f, 0.f};
        const float* w0 = &WT[(jb + j0) * 68];
#pragma unroll
        for (int q = 0; q < 16; q++) {
            float4 hv = h[q];
            float4 wa = *(const float4*)(w0 + 0 * 68 + 4 * q);
            float4 wb = *(const float4*)(w0 + 1 * 68 + 4 * q);
            float4 wc = *(const float4*)(w0 + 2 * 68 + 4 * q);
            float4 wd = *(const float4*)(w0 + 3 * 68 + 4 * q);
            acc.x = fmaf(hv.x, wa.x, acc.x); acc.x = fmaf(hv.y, wa.y, acc.x);
            acc.x = fmaf(hv.z, wa.z, acc.x); acc.x = fmaf(hv.w, wa.w, acc.x);
            acc.y = fmaf(hv.x, wb.x, acc.y); acc.y = fmaf(hv.y, wb.y, acc.y);
            acc.y = fmaf(hv.z, wb.z, acc.y); acc.y = fmaf(hv.w, wb.w, acc.y);
            acc.z = fmaf(hv.x, wc.x, acc.z); acc.z = fmaf(hv.y, wc.y, acc.z);
            acc.z = fmaf(hv.z, wc.z, acc.z); acc.z = fmaf(hv.w, wc.w, acc.z);
            acc.w = fmaf(hv.x, wd.x, acc.w); acc.w = fmaf(hv.y, wd.y, acc.w);
            acc.w = fmaf(hv.z, wd.z, acc.w); acc.w = fmaf(hv.w, wd.w, acc.w);
        }
        float4 y;
        y.x = fmaxf(fmaf(di, acc.x, b[jb + j0 + 0]), 0.f) * os;
        y.y = fmaxf(fmaf(di, acc.y, b[jb + j0 + 1]), 0.f) * os;
        y.z = fmaxf(fmaf(di, acc.z, b[jb + j0 + 2]), 0.f) * os;
        y.w = fmaxf(fmaf(di, acc.w, b[jb + j0 + 3]), 0.f) * os;
        if (outMode) {
            uint2 p;
            p.x = bfpack(y.x, y.y);
            p.y = bfpack(y.z, y.w);
            *(uint2*)(houtB + (size_t)i * 32 + ((jb + j0) >> 1)) = p;
        } else {
            *(float4*)(houtF + (size_t)i * 64 + jb + j0) = y;
        }
    }
}

// Thread per (node, head). tid<128 -> demand, tid>=128 -> inventory.
__global__ __launch_bounds__(256) void heads2(const float* __restrict__ h,
                                              const float* __restrict__ W_d1, const float* __restrict__ b_d1,
                                              const float* __restrict__ W_d2, const float* __restrict__ b_d2,
                                              const float* __restrict__ W_i1, const float* __restrict__ b_i1,
                                              const float* __restrict__ W_i2, const float* __restrict__ b_i2,
                                              float* __restrict__ out, int N) {
    __shared__ float WT[2][32 * 68];
    int tid = threadIdx.x;
    for (int e = tid; e < 2048; e += 256) {
        int k = e >> 5, j = e & 31;
        WT[0][j * 68 + k] = W_d1[e];
        WT[1][j * 68 + k] = W_i1[e];
    }
    __syncthreads();
    int head = tid >> 7;
    int i = blockIdx.x * 128 + (tid & 127);
    if (i >= N) return;
    float4 hr[16];
    const float4* h4 = (const float4*)(h + (size_t)i * 64);
#pragma unroll
    for (int q = 0; q < 16; q++) hr[q] = h4[q];
    const float* W1T = WT[head];
    const float* b1 = head ? b_i1 : b_d1;
    const float* W2 = head ? W_i2 : W_d2;
    float o = head ? b_i2[0] : b_d2[0];
#pragma unroll
    for (int j0 = 0; j0 < 32; j0 += 4) {
        float4 acc = {b1[j0], b1[j0 + 1], b1[j0 + 2], b1[j0 + 3]};
        const float* w0 = &W1T[j0 * 68];
#pragma unroll
        for (int q = 0; q < 16; q++) {
            float4 hv = hr[q];
            float4 wa = *(const float4*)(w0 + 0 * 68 + 4 * q);
            float4 wb = *(const float4*)(w0 + 1 * 68 + 4 * q);
            float4 wc = *(const float4*)(w0 + 2 * 68 + 4 * q);
            float4 wd = *(const float4*)(w0 + 3 * 68 + 4 * q);
            acc.x = fmaf(hv.x, wa.x, acc.x); acc.x = fmaf(hv.y, wa.y, acc.x);
            acc.x = fmaf(hv.z, wa.z, acc.x); acc.x = fmaf(hv.w, wa.w, acc.x);
            acc.y = fmaf(hv.x, wb.x, acc.y); acc.y = fmaf(hv.y, wb.y, acc.y);
            acc.y = fmaf(hv.z, wb.z, acc.y); acc.y = fmaf(hv.w, wb.w, acc.y);
            acc.z = fmaf(hv.x, wc.x, acc.z); acc.z = fmaf(hv.y, wc.y, acc.z);
            acc.z = fmaf(hv.z, wc.z, acc.z); acc.z = fmaf(hv.w, wc.w, acc.z);
            acc.w = fmaf(hv.x, wd.x, acc.w); acc.w = fmaf(hv.y, wd.y, acc.w);
            acc.w = fmaf(hv.z, wd.z, acc.w); acc.w = fmaf(hv.w, wd.w, acc.w);
        }
        o = fmaf(fmaxf(acc.x, 0.f), W2[j0 + 0], o);
        o = fmaf(fmaxf(acc.y, 0.f), W2[j0 + 1], o);
        o = fmaf(fmaxf(acc.z, 0.f), W2[j0 + 2], o);
        o = fmaf(fmaxf(acc.w, 0.f), W2[j0 + 3], o);
    }
    out[(size_t)head * N + i] = o;
}

extern "C" void kernel_launch(void* const* d_in, const int* in_sizes, int n_in,
                              void* d_out, int out_size, void* d_ws, size_t ws_size,
                              hipStream_t stream) {
    const float* x      = (const float*)d_in[0];
    const int*   ei     = (const int*)d_in[1];
    const float* W_enc  = (const float*)d_in[2];
    const float* b_enc  = (const float*)d_in[3];
    const float* conv_W = (const float*)d_in[4];
    const float* conv_b = (const float*)d_in[5];
    const float* W_d1   = (const float*)d_in[6];
    const float* b_d1   = (const float*)d_in[7];
    const float* W_d2   = (const float*)d_in[8];
    const float* b_d2   = (const float*)d_in[9];
    const float* W_i1   = (const float*)d_in[10];
    const float* b_i1   = (const float*)d_in[11];
    const float* W_i2   = (const float*)d_in[12];
    const float* b_i2   = (const float*)d_in[13];

    const int N = in_sizes[0] / 5;
    const int E = in_sizes[1] / 2;
    const int NB = (N + NPB - 1) >> NPB_SHIFT;   // 196 buckets

    float* g    = (float*)d_ws;                           // [N*64] fp32 (ebuf aliases)
    float* hfin = g + (size_t)N * HDIM;                   // [N*64] fp32
    unsigned* hbf = (unsigned*)(hfin + (size_t)N * HDIM); // [N*32] bf16x2
    float* dinv = (float*)(hbf + (size_t)N * 32);
    unsigned int* row_ptr = (unsigned int*)(dinv + N);    // [N+1]
    unsigned int* histT   = row_ptr + N + 1;              // [NB*PB]
    unsigned int* btot    = histT + (size_t)NB * PB;      // [NB]
    unsigned int* bbase   = btot + NB;                    // [NB+1]
    int* csr_src          = (int*)(bbase + NB + 1);       // [E]
    unsigned* ebuf        = (unsigned*)g;                 // [E] packed (dead before layer 0)
    float* out = (float*)d_out;

    const int hwBlocks = (N + 7) / 8;        // half-wave per node
    const int tnBlocks = (N + 127) / 128;    // 2 threads per node

    // CSR build: bucket sort, no global atomics, fully parallel scans
    hist_pass<<<PB, 256, 0, stream>>>(ei + E, histT, E, NB);
    scan_bucket<<<NB, 128, 0, stream>>>(histT, btot);
    scan_btot<<<1, 256, 0, stream>>>(btot, bbase, NB, E);
    bin_pass<<<PB, 256, 0, stream>>>(ei, histT, bbase, ebuf, E, NB);
    csr_pass<<<NB, 256, 0, stream>>>(ebuf, bbase, row_ptr, dinv, csr_src, N, E, NB);

    // encoder -> hn0 (bf16)
    encoder<<<(N * 32 + 255) / 256, 256, 0, stream>>>(x, W_enc, b_enc, dinv, hbf, N);

    // 3 GCN layers
    for (int l = 0; l < 3; l++) {
        gather3<<<hwBlocks, 256, 0, stream>>>(row_ptr, csr_src, hbf, g, N);
        conv_relu<<<tnBlocks, 256, 0, stream>>>(g, conv_W + l * HDIM * HDIM,
                                                conv_b + l * HDIM, dinv, hfin, hbf, N,
                                                (l < 2) ? 1 : 0);
    }

    // heads
    heads2<<<tnBlocks, 256, 0, stream>>>(hfin, W_d1, b_d1, W_d2, b_d2,
                                         W_i1, b_i1, W_i2, b_i2, out, N);
}

// Round 9
// 275.685 us; speedup vs baseline: 1.2637x; 1.0617x over previous
//
#include <hip/hip_runtime.h>
#include <hip/hip_bf16.h>

// SupplyChainGNN: 3-layer GCN, N=50000, E=800000, H=64.
// Round 8: mega-fused per-layer kernel (gather -> LDS -> conv -> [heads]):
// removes g/hfin inter-kernel round trips (~100MB) and 4 launches; scan_btot
// folded into bin/csr (each block re-scans the 196 bucket totals in LDS).
// hn double-buffered bf16x2 (fused kernel reads other nodes' hn_in).
// Requires N <= 65536 (u16 src packing), NB <= 256.

#define HDIM 64
#define PB 128          // blocks in hist/bin passes
#define NPB 256         // nodes per bucket
#define NPB_SHIFT 8

__device__ inline unsigned bfpack(float lo, float hi) {
    unsigned ul = __float_as_uint(lo), uh = __float_as_uint(hi);
    ul += 0x7fffu + ((ul >> 16) & 1u);
    uh += 0x7fffu + ((uh >> 16) & 1u);
    return (ul >> 16) | (uh & 0xffff0000u);
}

__device__ inline float2 bfunpack(unsigned u) {
    float2 r;
    r.x = __uint_as_float(u << 16);
    r.y = __uint_as_float(u & 0xffff0000u);
    return r;
}

// Pass 1: histT[k*PB + p] = #edges of block p with dst in bucket k  (NB<=256)
__global__ __launch_bounds__(256) void hist_pass(const int* __restrict__ dst,
                                                 unsigned* __restrict__ histT,
                                                 int E, int NB) {
    __shared__ unsigned h[256];
    int t = threadIdx.x, p = blockIdx.x;
    h[t] = 0u;
    __syncthreads();
    int chunk = (E + PB - 1) / PB;
    int lo = p * chunk, hi = min(lo + chunk, E);
    for (int e = lo + t; e < hi; e += 256)
        atomicAdd(&h[dst[e] >> NPB_SHIFT], 1u);
    __syncthreads();
    if (t < NB) histT[t * PB + p] = h[t];
}

// Pass 2: per-bucket exclusive scan of its PB per-block counts (in place);
// bucket total -> btot[k].
__global__ __launch_bounds__(128) void scan_bucket(unsigned* __restrict__ histT,
                                                   unsigned* __restrict__ btot) {
    __shared__ unsigned s[PB];
    int t = threadIdx.x, k = blockIdx.x;
    unsigned v = histT[k * PB + t];
    s[t] = v;
    __syncthreads();
#pragma unroll
    for (int off = 1; off < PB; off <<= 1) {
        unsigned u = (t >= off) ? s[t - off] : 0u;
        __syncthreads();
        s[t] += u;
        __syncthreads();
    }
    histT[k * PB + t] = s[t] - v;
    if (t == PB - 1) btot[k] = s[t];
}

// Pass 3: scatter packed (dst_local<<16)|src into bucket-grouped ebuf.
// Each block re-derives bbase via a 256-entry LDS scan of btot.
__global__ __launch_bounds__(256) void bin_pass(const int* __restrict__ ei,
                                                const unsigned* __restrict__ histT,
                                                const unsigned* __restrict__ btot,
                                                unsigned* __restrict__ ebuf,
                                                int E, int NB) {
    __shared__ unsigned bb[256];
    __shared__ unsigned cur[256];
    int t = threadIdx.x, p = blockIdx.x;
    unsigned bv = (t < NB) ? btot[t] : 0u;
    bb[t] = bv;
    __syncthreads();
#pragma unroll
    for (int off = 1; off < 256; off <<= 1) {
        unsigned u = (t >= off) ? bb[t - off] : 0u;
        __syncthreads();
        bb[t] += u;
        __syncthreads();
    }
    if (t < NB) cur[t] = histT[t * PB + p] + (bb[t] - bv);
    __syncthreads();
    int chunk = (E + PB - 1) / PB;
    int lo = p * chunk, hi = min(lo + chunk, E);
    for (int e = lo + t; e < hi; e += 256) {
        unsigned sN = (unsigned)ei[e];
        unsigned dN = (unsigned)ei[E + e];
        unsigned pos = atomicAdd(&cur[dN >> NPB_SHIFT], 1u);
        ebuf[pos] = ((dN & (NPB - 1u)) << 16) | sN;
    }
}

// Pass 4: one block per bucket -> row_ptr, dinv, csr_src. Re-derives its
// e0/e1 from a local scan of btot.
__global__ __launch_bounds__(256) void csr_pass(const unsigned* __restrict__ ebuf,
                                                const unsigned* __restrict__ btot,
                                                unsigned* __restrict__ row_ptr,
                                                float* __restrict__ dinv,
                                                int* __restrict__ csr_src,
                                                int N, int E, int NB) {
    __shared__ unsigned bb[256];
    __shared__ unsigned cntL[NPB];
    __shared__ unsigned sc[NPB];
    __shared__ unsigned cur[NPB];
    int t = threadIdx.x, k = blockIdx.x;
    unsigned bv = (t < NB) ? btot[t] : 0u;
    bb[t] = bv;
    __syncthreads();
#pragma unroll
    for (int off = 1; off < 256; off <<= 1) {
        unsigned u = (t >= off) ? bb[t - off] : 0u;
        __syncthreads();
        bb[t] += u;
        __syncthreads();
    }
    unsigned e1 = bb[k];
    unsigned e0 = e1 - btot[k];
    int nbase = k << NPB_SHIFT;
    cntL[t] = 0u;
    __syncthreads();
    for (unsigned e = e0 + t; e < e1; e += 256)
        atomicAdd(&cntL[ebuf[e] >> 16], 1u);
    __syncthreads();
    unsigned v = cntL[t];
    sc[t] = v;
    __syncthreads();
#pragma unroll
    for (int off = 1; off < NPB; off <<= 1) {
        unsigned u = (t >= off) ? sc[t - off] : 0u;
        __syncthreads();
        sc[t] += u;
        __syncthreads();
    }
    unsigned pos0 = e0 + sc[t] - v;
    cur[t] = pos0;
    int node = nbase + t;
    if (node < N) {
        row_ptr[node] = pos0;
        dinv[node] = rsqrtf((float)(v + 1u));
    }
    if (k == NB - 1 && t == 0) row_ptr[N] = (unsigned)E;
    __syncthreads();
    for (unsigned e = e0 + t; e < e1; e += 256) {
        unsigned ed = ebuf[e];
        unsigned pos = atomicAdd(&cur[ed >> 16], 1u);
        csr_src[pos] = (int)(ed & 0xffffu);
    }
}

// hn[i] = bf16( dinv[i] * relu(x@W+b) ); thread per feature-pair.
__global__ __launch_bounds__(256) void encoder(const float* __restrict__ x,
                                               const float* __restrict__ W,
                                               const float* __restrict__ b,
                                               const float* __restrict__ dinv,
                                               unsigned* __restrict__ hn, int N) {
    int t = blockIdx.x * 256 + threadIdx.x;
    int i = t >> 5, jp = t & 31;
    if (i >= N) return;
    int j0 = 2 * jp;
    float a0 = b[j0], a1 = b[j0 + 1];
#pragma unroll
    for (int k = 0; k < 5; k++) {
        float xv = x[i * 5 + k];
        a0 = fmaf(xv, W[k * 64 + j0], a0);
        a1 = fmaf(xv, W[k * 64 + j0 + 1], a1);
    }
    float di = dinv[i];
    hn[t] = bfpack(di * fmaxf(a0, 0.0f), di * fmaxf(a1, 0.0f));
}

// Fused layer: block = 8 half-waves = 8 nodes.
//   phase 1 (gather): half-wave gathers its node's edge sum into regs -> gbuf.
//   phase 2 (conv):   thread t = (node hw, outputs 2fl..2fl+1) from LDS.
//   mode 0/1: hn_out = bf16(dinv * relu(dinv*(g@W)+b))
//   mode 2:   row -> hbuf, then both MLP heads inline -> out[0..N), out[N..2N)
__global__ __launch_bounds__(256) void layer_fused(
    const unsigned* __restrict__ row_ptr, const int* __restrict__ csr_src,
    const unsigned* __restrict__ hn_in, const float* __restrict__ W,
    const float* __restrict__ b, const float* __restrict__ dinv,
    unsigned* __restrict__ hn_out, int N, int mode,
    const float* __restrict__ W_d1, const float* __restrict__ b_d1,
    const float* __restrict__ W_d2, const float* __restrict__ b_d2,
    const float* __restrict__ W_i1, const float* __restrict__ b_i1,
    const float* __restrict__ W_i2, const float* __restrict__ b_i2,
    float* __restrict__ out) {
    extern __shared__ float sm[];
    float* Ws   = sm;              // 4096 floats (conv W, k-major [k][j])
    float* gbuf = Ws + 4096;       // 8 * 68
    float* Wh   = gbuf + 544;      // mode2: 2 * 2048 ([k][j], 64x32 each)
    float* hbuf = Wh + 4096;       // mode2: 8 * 68
    int tid = threadIdx.x;
    {
        const float4* W4 = (const float4*)W;
        float4* Ws4 = (float4*)Ws;
#pragma unroll
        for (int r = 0; r < 4; r++) Ws4[r * 256 + tid] = W4[r * 256 + tid];
    }
    if (mode == 2) {
        for (int e = tid; e < 2048; e += 256) {
            Wh[e] = W_d1[e];
            Wh[2048 + e] = W_i1[e];
        }
    }
    int hw = tid >> 5, fl = tid & 31;
    int i = blockIdx.x * 8 + hw;
    if (i < N) {
        // ---- gather (R7 structure) ----
        float2 a0 = bfunpack(hn_in[(size_t)i * 32 + fl]);
        float2 a1 = {0.f, 0.f}, a2 = {0.f, 0.f}, a3 = {0.f, 0.f};
        float2 a4 = {0.f, 0.f}, a5 = {0.f, 0.f}, a6 = {0.f, 0.f}, a7 = {0.f, 0.f};
        unsigned e0 = row_ptr[i];
        unsigned cnt = row_ptr[i + 1] - e0;
        const int* idx = csr_src + e0;
        unsigned u = 0;
        for (; u + 8 <= cnt; u += 8) {
            int s0 = idx[u + 0], s1 = idx[u + 1], s2 = idx[u + 2], s3 = idx[u + 3];
            int s4 = idx[u + 4], s5 = idx[u + 5], s6 = idx[u + 6], s7 = idx[u + 7];
            unsigned v0 = hn_in[(size_t)s0 * 32 + fl];
            unsigned v1 = hn_in[(size_t)s1 * 32 + fl];
            unsigned v2 = hn_in[(size_t)s2 * 32 + fl];
            unsigned v3 = hn_in[(size_t)s3 * 32 + fl];
            unsigned v4 = hn_in[(size_t)s4 * 32 + fl];
            unsigned v5 = hn_in[(size_t)s5 * 32 + fl];
            unsigned v6 = hn_in[(size_t)s6 * 32 + fl];
            unsigned v7 = hn_in[(size_t)s7 * 32 + fl];
            float2 f0 = bfunpack(v0), f1 = bfunpack(v1), f2 = bfunpack(v2), f3 = bfunpack(v3);
            float2 f4 = bfunpack(v4), f5 = bfunpack(v5), f6 = bfunpack(v6), f7 = bfunpack(v7);
            a0.x += f0.x; a0.y += f0.y;  a1.x += f1.x; a1.y += f1.y;
            a2.x += f2.x; a2.y += f2.y;  a3.x += f3.x; a3.y += f3.y;
            a4.x += f4.x; a4.y += f4.y;  a5.x += f5.x; a5.y += f5.y;
            a6.x += f6.x; a6.y += f6.y;  a7.x += f7.x; a7.y += f7.y;
        }
        for (; u < cnt; u++) {
            float2 f = bfunpack(hn_in[(size_t)idx[u] * 32 + fl]);
            a0.x += f.x; a0.y += f.y;
        }
        a0.x += a1.x; a0.y += a1.y;  a2.x += a3.x; a2.y += a3.y;
        a4.x += a5.x; a4.y += a5.y;  a6.x += a7.x; a6.y += a7.y;
        a0.x += a2.x; a0.y += a2.y;  a4.x += a6.x; a4.y += a6.y;
        a0.x += a4.x; a0.y += a4.y;
        ((float2*)(gbuf + hw * 68))[fl] = a0;
    }
    __syncthreads();
    // ---- conv from LDS ----
    float di = (i < N) ? dinv[i] : 0.f;
    const float2* Ws2 = (const float2*)Ws;
    const float* gr = gbuf + hw * 68;
    float2 acc0 = {0.f, 0.f}, acc1 = {0.f, 0.f};
#pragma unroll
    for (int k = 0; k < 64; k += 2) {
        float g0 = gr[k], g1 = gr[k + 1];
        float2 w0 = Ws2[k * 32 + fl];
        float2 w1 = Ws2[(k + 1) * 32 + fl];
        acc0.x = fmaf(g0, w0.x, acc0.x); acc0.y = fmaf(g0, w0.y, acc0.y);
        acc1.x = fmaf(g1, w1.x, acc1.x); acc1.y = fmaf(g1, w1.y, acc1.y);
    }
    int j0 = 2 * fl;
    float yx = fmaxf(fmaf(di, acc0.x + acc1.x, b[j0]), 0.f);
    float yy = fmaxf(fmaf(di, acc0.y + acc1.y, b[j0 + 1]), 0.f);
    if (mode != 2) {
        if (i < N) hn_out[(size_t)i * 32 + fl] = bfpack(yx * di, yy * di);
    } else {
        ((float2*)(hbuf + hw * 68))[fl] = make_float2(yx, yy);
        __syncthreads();
        const float* hr = hbuf + hw * 68;
#pragma unroll
        for (int hd = 0; hd < 2; hd++) {
            const float* W1 = Wh + hd * 2048;
            float p0 = 0.f, p1 = 0.f, p2 = 0.f, p3 = 0.f;
#pragma unroll
            for (int k = 0; k < 64; k += 4) {
                p0 = fmaf(hr[k + 0], W1[(k + 0) * 32 + fl], p0);
                p1 = fmaf(hr[k + 1], W1[(k + 1) * 32 + fl], p1);
                p2 = fmaf(hr[k + 2], W1[(k + 2) * 32 + fl], p2);
                p3 = fmaf(hr[k + 3], W1[(k + 3) * 32 + fl], p3);
            }
            float a = (hd ? b_i1[fl] : b_d1[fl]) + ((p0 + p1) + (p2 + p3));
            float o = fmaxf(a, 0.f) * (hd ? W_i2[fl] : W_d2[fl]);
#pragma unroll
            for (int off = 16; off >= 1; off >>= 1) o += __shfl_xor(o, off, 64);
            if (fl == 0 && i < N) out[(size_t)hd * N + i] = o + (hd ? b_i2[0] : b_d2[0]);
        }
    }
}

extern "C" void kernel_launch(void* const* d_in, const int* in_sizes, int n_in,
                              void* d_out, int out_size, void* d_ws, size_t ws_size,
                              hipStream_t stream) {
    const float* x      = (const float*)d_in[0];
    const int*   ei     = (const int*)d_in[1];
    const float* W_enc  = (const float*)d_in[2];
    const float* b_enc  = (const float*)d_in[3];
    const float* conv_W = (const float*)d_in[4];
    const float* conv_b = (const float*)d_in[5];
    const float* W_d1   = (const float*)d_in[6];
    const float* b_d1   = (const float*)d_in[7];
    const float* W_d2   = (const float*)d_in[8];
    const float* b_d2   = (const float*)d_in[9];
    const float* W_i1   = (const float*)d_in[10];
    const float* b_i1   = (const float*)d_in[11];
    const float* W_i2   = (const float*)d_in[12];
    const float* b_i2   = (const float*)d_in[13];

    const int N = in_sizes[0] / 5;
    const int E = in_sizes[1] / 2;
    const int NB = (N + NPB - 1) >> NPB_SHIFT;   // <= 256

    unsigned* hnA = (unsigned*)d_ws;                     // [N*32] bf16x2
    unsigned* hnB = hnA + (size_t)N * 32;                // [N*32]
    float* dinv   = (float*)(hnB + (size_t)N * 32);      // [N]
    unsigned* row_ptr = (unsigned*)(dinv + N);           // [N+1]
    unsigned* histT   = row_ptr + N + 1;                 // [NB*PB]
    unsigned* btot    = histT + (size_t)NB * PB;         // [NB]
    int* csr_src      = (int*)(btot + NB);               // [E]
    unsigned* ebuf    = (unsigned*)(csr_src + E);        // [E] packed
    float* out = (float*)d_out;

    const int lfBlocks = (N + 7) / 8;
    const size_t smSmall = (4096 + 544) * sizeof(float);
    const size_t smBig   = (4096 + 544 + 4096 + 544) * sizeof(float);

    // CSR build
    hist_pass<<<PB, 256, 0, stream>>>(ei + E, histT, E, NB);
    scan_bucket<<<NB, 128, 0, stream>>>(histT, btot);
    bin_pass<<<PB, 256, 0, stream>>>(ei, histT, btot, ebuf, E, NB);
    csr_pass<<<NB, 256, 0, stream>>>(ebuf, btot, row_ptr, dinv, csr_src, N, E, NB);

    // encoder -> hnA
    encoder<<<(N * 32 + 255) / 256, 256, 0, stream>>>(x, W_enc, b_enc, dinv, hnA, N);

    // layer 0: hnA -> hnB ; layer 1: hnB -> hnA ; layer 2: hnA -> heads/out
    layer_fused<<<lfBlocks, 256, smSmall, stream>>>(
        row_ptr, csr_src, hnA, conv_W + 0 * 4096, conv_b + 0 * 64, dinv, hnB, N, 0,
        nullptr, nullptr, nullptr, nullptr, nullptr, nullptr, nullptr, nullptr, nullptr);
    layer_fused<<<lfBlocks, 256, smSmall, stream>>>(
        row_ptr, csr_src, hnB, conv_W + 1 * 4096, conv_b + 1 * 64, dinv, hnA, N, 1,
        nullptr, nullptr, nullptr, nullptr, nullptr, nullptr, nullptr, nullptr, nullptr);
    layer_fused<<<lfBlocks, 256, smBig, stream>>>(
        row_ptr, csr_src, hnA, conv_W + 2 * 4096, conv_b + 2 * 64, dinv, nullptr, N, 2,
        W_d1, b_d1, W_d2, b_d2, W_i1, b_i1, W_i2, b_i2, out);
}

// Round 10
// 274.890 us; speedup vs baseline: 1.2674x; 1.0029x over previous
//
#include <hip/hip_runtime.h>
#include <hip/hip_bf16.h>

// SupplyChainGNN: 3-layer GCN, N=50000, E=800000, H=64.
// Round 9: un-fuse (R8 fused conv had per-lane LDS W reads = 32KB/node tax;
// R7 separate conv uses broadcast W^T = free). Gather fixed for memory-level
// parallelism: __launch_bounds__(256,4) lifts the VGPR cap to 128 (R8's 32
// VGPRs forced load serialization -> ~75us latency-bound layers); remainder
// handled as one predicated parallel batch instead of a serial scalar loop.
// CSR build = R8's 4-pass bucket sort (scan_btot folded into bin/csr).

#define HDIM 64
#define PB 128          // blocks in hist/bin passes
#define NPB 256         // nodes per bucket
#define NPB_SHIFT 8

__device__ inline unsigned bfpack(float lo, float hi) {
    unsigned ul = __float_as_uint(lo), uh = __float_as_uint(hi);
    ul += 0x7fffu + ((ul >> 16) & 1u);
    uh += 0x7fffu + ((uh >> 16) & 1u);
    return (ul >> 16) | (uh & 0xffff0000u);
}

__device__ inline float2 bfunpack(unsigned u) {
    float2 r;
    r.x = __uint_as_float(u << 16);
    r.y = __uint_as_float(u & 0xffff0000u);
    return r;
}

// Pass 1: histT[k*PB + p] = #edges of block p with dst in bucket k  (NB<=256)
__global__ __launch_bounds__(256) void hist_pass(const int* __restrict__ dst,
                                                 unsigned* __restrict__ histT,
                                                 int E, int NB) {
    __shared__ unsigned h[256];
    int t = threadIdx.x, p = blockIdx.x;
    h[t] = 0u;
    __syncthreads();
    int chunk = (E + PB - 1) / PB;
    int lo = p * chunk, hi = min(lo + chunk, E);
    for (int e = lo + t; e < hi; e += 256)
        atomicAdd(&h[dst[e] >> NPB_SHIFT], 1u);
    __syncthreads();
    if (t < NB) histT[t * PB + p] = h[t];
}

// Pass 2: per-bucket exclusive scan of its PB per-block counts (in place);
// bucket total -> btot[k].
__global__ __launch_bounds__(128) void scan_bucket(unsigned* __restrict__ histT,
                                                   unsigned* __restrict__ btot) {
    __shared__ unsigned s[PB];
    int t = threadIdx.x, k = blockIdx.x;
    unsigned v = histT[k * PB + t];
    s[t] = v;
    __syncthreads();
#pragma unroll
    for (int off = 1; off < PB; off <<= 1) {
        unsigned u = (t >= off) ? s[t - off] : 0u;
        __syncthreads();
        s[t] += u;
        __syncthreads();
    }
    histT[k * PB + t] = s[t] - v;
    if (t == PB - 1) btot[k] = s[t];
}

// Pass 3: scatter packed (dst_local<<16)|src into bucket-grouped ebuf.
// Each block re-derives bbase via a 256-entry LDS scan of btot.
__global__ __launch_bounds__(256) void bin_pass(const int* __restrict__ ei,
                                                const unsigned* __restrict__ histT,
                                                const unsigned* __restrict__ btot,
                                                unsigned* __restrict__ ebuf,
                                                int E, int NB) {
    __shared__ unsigned bb[256];
    __shared__ unsigned cur[256];
    int t = threadIdx.x, p = blockIdx.x;
    unsigned bv = (t < NB) ? btot[t] : 0u;
    bb[t] = bv;
    __syncthreads();
#pragma unroll
    for (int off = 1; off < 256; off <<= 1) {
        unsigned u = (t >= off) ? bb[t - off] : 0u;
        __syncthreads();
        bb[t] += u;
        __syncthreads();
    }
    if (t < NB) cur[t] = histT[t * PB + p] + (bb[t] - bv);
    __syncthreads();
    int chunk = (E + PB - 1) / PB;
    int lo = p * chunk, hi = min(lo + chunk, E);
    for (int e = lo + t; e < hi; e += 256) {
        unsigned sN = (unsigned)ei[e];
        unsigned dN = (unsigned)ei[E + e];
        unsigned pos = atomicAdd(&cur[dN >> NPB_SHIFT], 1u);
        ebuf[pos] = ((dN & (NPB - 1u)) << 16) | sN;
    }
}

// Pass 4: one block per bucket -> row_ptr, dinv, csr_src.
__global__ __launch_bounds__(256) void csr_pass(const unsigned* __restrict__ ebuf,
                                                const unsigned* __restrict__ btot,
                                                unsigned* __restrict__ row_ptr,
                                                float* __restrict__ dinv,
                                                int* __restrict__ csr_src,
                                                int N, int E, int NB) {
    __shared__ unsigned bb[256];
    __shared__ unsigned cntL[NPB];
    __shared__ unsigned sc[NPB];
    __shared__ unsigned cur[NPB];
    int t = threadIdx.x, k = blockIdx.x;
    unsigned bv = (t < NB) ? btot[t] : 0u;
    bb[t] = bv;
    __syncthreads();
#pragma unroll
    for (int off = 1; off < 256; off <<= 1) {
        unsigned u = (t >= off) ? bb[t - off] : 0u;
        __syncthreads();
        bb[t] += u;
        __syncthreads();
    }
    unsigned e1 = bb[k];
    unsigned e0 = e1 - btot[k];
    int nbase = k << NPB_SHIFT;
    cntL[t] = 0u;
    __syncthreads();
    for (unsigned e = e0 + t; e < e1; e += 256)
        atomicAdd(&cntL[ebuf[e] >> 16], 1u);
    __syncthreads();
    unsigned v = cntL[t];
    sc[t] = v;
    __syncthreads();
#pragma unroll
    for (int off = 1; off < NPB; off <<= 1) {
        unsigned u = (t >= off) ? sc[t - off] : 0u;
        __syncthreads();
        sc[t] += u;
        __syncthreads();
    }
    unsigned pos0 = e0 + sc[t] - v;
    cur[t] = pos0;
    int node = nbase + t;
    if (node < N) {
        row_ptr[node] = pos0;
        dinv[node] = rsqrtf((float)(v + 1u));
    }
    if (k == NB - 1 && t == 0) row_ptr[N] = (unsigned)E;
    __syncthreads();
    for (unsigned e = e0 + t; e < e1; e += 256) {
        unsigned ed = ebuf[e];
        unsigned pos = atomicAdd(&cur[ed >> 16], 1u);
        csr_src[pos] = (int)(ed & 0xffffu);
    }
}

// hn[i] = bf16( dinv[i] * relu(x@W+b) ); thread per feature-pair.
__global__ __launch_bounds__(256) void encoder(const float* __restrict__ x,
                                               const float* __restrict__ W,
                                               const float* __restrict__ b,
                                               const float* __restrict__ dinv,
                                               unsigned* __restrict__ hn, int N) {
    int t = blockIdx.x * 256 + threadIdx.x;
    int i = t >> 5, jp = t & 31;
    if (i >= N) return;
    int j0 = 2 * jp;
    float a0 = b[j0], a1 = b[j0 + 1];
#pragma unroll
    for (int k = 0; k < 5; k++) {
        float xv = x[i * 5 + k];
        a0 = fmaf(xv, W[k * 64 + j0], a0);
        a1 = fmaf(xv, W[k * 64 + j0 + 1], a1);
    }
    float di = dinv[i];
    hn[t] = bfpack(di * fmaxf(a0, 0.0f), di * fmaxf(a1, 0.0f));
}

// Half-wave (32 lanes) per node. launch_bounds(256,4) -> VGPR cap 128 so the
// 8 idx + 8 row loads stay concurrently in flight (32-VGPR builds serialize
// them -> 5x slower). Remainder = one predicated parallel batch (indices
// clamped to last valid, adds masked).
__global__ __launch_bounds__(256, 4) void gather3(const unsigned int* __restrict__ row_ptr,
                                                  const int* __restrict__ csr_src,
                                                  const unsigned* __restrict__ hn,
                                                  float* __restrict__ g, int N) {
    int t = blockIdx.x * 256 + threadIdx.x;
    int i = t >> 5;
    if (i >= N) return;
    int fl = t & 31;
    float2 a0 = bfunpack(hn[(size_t)i * 32 + fl]);  // self term
    float2 a1 = {0.f, 0.f}, a2 = {0.f, 0.f}, a3 = {0.f, 0.f};
    float2 a4 = {0.f, 0.f}, a5 = {0.f, 0.f}, a6 = {0.f, 0.f}, a7 = {0.f, 0.f};
    unsigned e0 = row_ptr[i];
    unsigned cnt = row_ptr[i + 1] - e0;
    const int* idx = csr_src + e0;
    unsigned u = 0;
    for (; u + 8 <= cnt; u += 8) {
        int s0 = idx[u + 0], s1 = idx[u + 1], s2 = idx[u + 2], s3 = idx[u + 3];
        int s4 = idx[u + 4], s5 = idx[u + 5], s6 = idx[u + 6], s7 = idx[u + 7];
        unsigned v0 = hn[(size_t)s0 * 32 + fl];
        unsigned v1 = hn[(size_t)s1 * 32 + fl];
        unsigned v2 = hn[(size_t)s2 * 32 + fl];
        unsigned v3 = hn[(size_t)s3 * 32 + fl];
        unsigned v4 = hn[(size_t)s4 * 32 + fl];
        unsigned v5 = hn[(size_t)s5 * 32 + fl];
        unsigned v6 = hn[(size_t)s6 * 32 + fl];
        unsigned v7 = hn[(size_t)s7 * 32 + fl];
        float2 f0 = bfunpack(v0), f1 = bfunpack(v1), f2 = bfunpack(v2), f3 = bfunpack(v3);
        float2 f4 = bfunpack(v4), f5 = bfunpack(v5), f6 = bfunpack(v6), f7 = bfunpack(v7);
        a0.x += f0.x; a0.y += f0.y;  a1.x += f1.x; a1.y += f1.y;
        a2.x += f2.x; a2.y += f2.y;  a3.x += f3.x; a3.y += f3.y;
        a4.x += f4.x; a4.y += f4.y;  a5.x += f5.x; a5.y += f5.y;
        a6.x += f6.x; a6.y += f6.y;  a7.x += f7.x; a7.y += f7.y;
    }
    if (u < cnt) {  // predicated parallel remainder (1..7 edges)
        unsigned last = cnt - 1;
        int s0 = idx[u];
        int s1 = idx[min(u + 1, last)];
        int s2 = idx[min(u + 2, last)];
        int s3 = idx[min(u + 3, last)];
        int s4 = idx[min(u + 4, last)];
        int s5 = idx[min(u + 5, last)];
        int s6 = idx[min(u + 6, last)];
        int s7 = idx[min(u + 7, last)];
        unsigned v0 = hn[(size_t)s0 * 32 + fl];
        unsigned v1 = hn[(size_t)s1 * 32 + fl];
        unsigned v2 = hn[(size_t)s2 * 32 + fl];
        unsigned v3 = hn[(size_t)s3 * 32 + fl];
        unsigned v4 = hn[(size_t)s4 * 32 + fl];
        unsigned v5 = hn[(size_t)s5 * 32 + fl];
        unsigned v6 = hn[(size_t)s6 * 32 + fl];
        unsigned v7 = hn[(size_t)s7 * 32 + fl];
        float2 f0 = bfunpack(v0), f1 = bfunpack(v1), f2 = bfunpack(v2), f3 = bfunpack(v3);
        float2 f4 = bfunpack(v4), f5 = bfunpack(v5), f6 = bfunpack(v6), f7 = bfunpack(v7);
        a0.x += f0.x;                  a0.y += f0.y;
        a1.x += (u + 1 < cnt) ? f1.x : 0.f;  a1.y += (u + 1 < cnt) ? f1.y : 0.f;
        a2.x += (u + 2 < cnt) ? f2.x : 0.f;  a2.y += (u + 2 < cnt) ? f2.y : 0.f;
        a3.x += (u + 3 < cnt) ? f3.x : 0.f;  a3.y += (u + 3 < cnt) ? f3.y : 0.f;
        a4.x += (u + 4 < cnt) ? f4.x : 0.f;  a4.y += (u + 4 < cnt) ? f4.y : 0.f;
        a5.x += (u + 5 < cnt) ? f5.x : 0.f;  a5.y += (u + 5 < cnt) ? f5.y : 0.f;
        a6.x += (u + 6 < cnt) ? f6.x : 0.f;  a6.y += (u + 6 < cnt) ? f6.y : 0.f;
        a7.x += (u + 7 < cnt) ? f7.x : 0.f;  a7.y += (u + 7 < cnt) ? f7.y : 0.f;
    }
    a0.x += a1.x; a0.y += a1.y;  a2.x += a3.x; a2.y += a3.y;
    a4.x += a5.x; a4.y += a5.y;  a6.x += a7.x; a6.y += a7.y;
    a0.x += a2.x; a0.y += a2.y;  a4.x += a6.x; a4.y += a6.y;
    a0.x += a4.x; a0.y += a4.y;
    float2* g2 = (float2*)g;
    g2[(size_t)i * 32 + fl] = a0;
}

// Thread per (node, output-half). Row of g (fp32) in VGPRs; W^T in LDS
// (wave-uniform broadcast ds_read_b128 -> no LDS BW tax).
// outMode=1: write bf16 hn_next = dinv*relu(...)  (layers 0,1)
// outMode=0: write fp32 h = relu(...)             (layer 2, feeds heads)
__global__ __launch_bounds__(256) void conv_relu(const float* __restrict__ g,
                                                 const float* __restrict__ W,
                                                 const float* __restrict__ b,
                                                 const float* __restrict__ dinv,
                                                 float* __restrict__ houtF,
                                                 unsigned* __restrict__ houtB,
                                                 int N, int outMode) {
    __shared__ float WT[64 * 68];
    int tid = threadIdx.x;
    for (int e = tid; e < 4096; e += 256) {
        int k = e >> 6, j = e & 63;
        WT[j * 68 + k] = W[e];
    }
    __syncthreads();
    int half = tid >> 7;
    int i = blockIdx.x * 128 + (tid & 127);
    if (i >= N) return;
    float4 h[16];
    const float4* g4 = (const float4*)(g + (size_t)i * 64);
#pragma unroll
    for (int q = 0; q < 16; q++) h[q] = g4[q];
    float di = dinv[i];
    float os = outMode ? di : 1.0f;
    int jb = half * 32;
#pragma unroll
    for (int j0 = 0; j0 < 32; j0 += 4) {
        float4 acc = {0.f, 0.f, 0.f, 0.f};
        const float* w0 = &WT[(jb + j0) * 68];
#pragma unroll
        for (int q = 0; q < 16; q++) {
            float4 hv = h[q];
            float4 wa = *(const float4*)(w0 + 0 * 68 + 4 * q);
            float4 wb = *(const float4*)(w0 + 1 * 68 + 4 * q);
            float4 wc = *(const float4*)(w0 + 2 * 68 + 4 * q);
            float4 wd = *(const float4*)(w0 + 3 * 68 + 4 * q);
            acc.x = fmaf(hv.x, wa.x, acc.x); acc.x = fmaf(hv.y, wa.y, acc.x);
            acc.x = fmaf(hv.z, wa.z, acc.x); acc.x = fmaf(hv.w, wa.w, acc.x);
            acc.y = fmaf(hv.x, wb.x, acc.y); acc.y = fmaf(hv.y, wb.y, acc.y);
            acc.y = fmaf(hv.z, wb.z, acc.y); acc.y = fmaf(hv.w, wb.w, acc.y);
            acc.z = fmaf(hv.x, wc.x, acc.z); acc.z = fmaf(hv.y, wc.y, acc.z);
            acc.z = fmaf(hv.z, wc.z, acc.z); acc.z = fmaf(hv.w, wc.w, acc.z);
            acc.w = fmaf(hv.x, wd.x, acc.w); acc.w = fmaf(hv.y, wd.y, acc.w);
            acc.w = fmaf(hv.z, wd.z, acc.w); acc.w = fmaf(hv.w, wd.w, acc.w);
        }
        float4 y;
        y.x = fmaxf(fmaf(di, acc.x, b[jb + j0 + 0]), 0.f) * os;
        y.y = fmaxf(fmaf(di, acc.y, b[jb + j0 + 1]), 0.f) * os;
        y.z = fmaxf(fmaf(di, acc.z, b[jb + j0 + 2]), 0.f) * os;
        y.w = fmaxf(fmaf(di, acc.w, b[jb + j0 + 3]), 0.f) * os;
        if (outMode) {
            uint2 p;
            p.x = bfpack(y.x, y.y);
            p.y = bfpack(y.z, y.w);
            *(uint2*)(houtB + (size_t)i * 32 + ((jb + j0) >> 1)) = p;
        } else {
            *(float4*)(houtF + (size_t)i * 64 + jb + j0) = y;
        }
    }
}

// Thread per (node, head). tid<128 -> demand, tid>=128 -> inventory.
__global__ __launch_bounds__(256) void heads2(const float* __restrict__ h,
                                              const float* __restrict__ W_d1, const float* __restrict__ b_d1,
                                              const float* __restrict__ W_d2, const float* __restrict__ b_d2,
                                              const float* __restrict__ W_i1, const float* __restrict__ b_i1,
                                              const float* __restrict__ W_i2, const float* __restrict__ b_i2,
                                              float* __restrict__ out, int N) {
    __shared__ float WT[2][32 * 68];
    int tid = threadIdx.x;
    for (int e = tid; e < 2048; e += 256) {
        int k = e >> 5, j = e & 31;
        WT[0][j * 68 + k] = W_d1[e];
        WT[1][j * 68 + k] = W_i1[e];
    }
    __syncthreads();
    int head = tid >> 7;
    int i = blockIdx.x * 128 + (tid & 127);
    if (i >= N) return;
    float4 hr[16];
    const float4* h4 = (const float4*)(h + (size_t)i * 64);
#pragma unroll
    for (int q = 0; q < 16; q++) hr[q] = h4[q];
    const float* W1T = WT[head];
    const float* b1 = head ? b_i1 : b_d1;
    const float* W2 = head ? W_i2 : W_d2;
    float o = head ? b_i2[0] : b_d2[0];
#pragma unroll
    for (int j0 = 0; j0 < 32; j0 += 4) {
        float4 acc = {b1[j0], b1[j0 + 1], b1[j0 + 2], b1[j0 + 3]};
        const float* w0 = &W1T[j0 * 68];
#pragma unroll
        for (int q = 0; q < 16; q++) {
            float4 hv = hr[q];
            float4 wa = *(const float4*)(w0 + 0 * 68 + 4 * q);
            float4 wb = *(const float4*)(w0 + 1 * 68 + 4 * q);
            float4 wc = *(const float4*)(w0 + 2 * 68 + 4 * q);
            float4 wd = *(const float4*)(w0 + 3 * 68 + 4 * q);
            acc.x = fmaf(hv.x, wa.x, acc.x); acc.x = fmaf(hv.y, wa.y, acc.x);
            acc.x = fmaf(hv.z, wa.z, acc.x); acc.x = fmaf(hv.w, wa.w, acc.x);
            acc.y = fmaf(hv.x, wb.x, acc.y); acc.y = fmaf(hv.y, wb.y, acc.y);
            acc.y = fmaf(hv.z, wb.z, acc.y); acc.y = fmaf(hv.w, wb.w, acc.y);
            acc.z = fmaf(hv.x, wc.x, acc.z); acc.z = fmaf(hv.y, wc.y, acc.z);
            acc.z = fmaf(hv.z, wc.z, acc.z); acc.z = fmaf(hv.w, wc.w, acc.z);
            acc.w = fmaf(hv.x, wd.x, acc.w); acc.w = fmaf(hv.y, wd.y, acc.w);
            acc.w = fmaf(hv.z, wd.z, acc.w); acc.w = fmaf(hv.w, wd.w, acc.w);
        }
        o = fmaf(fmaxf(acc.x, 0.f), W2[j0 + 0], o);
        o = fmaf(fmaxf(acc.y, 0.f), W2[j0 + 1], o);
        o = fmaf(fmaxf(acc.z, 0.f), W2[j0 + 2], o);
        o = fmaf(fmaxf(acc.w, 0.f), W2[j0 + 3], o);
    }
    out[(size_t)head * N + i] = o;
}

extern "C" void kernel_launch(void* const* d_in, const int* in_sizes, int n_in,
                              void* d_out, int out_size, void* d_ws, size_t ws_size,
                              hipStream_t stream) {
    const float* x      = (const float*)d_in[0];
    const int*   ei     = (const int*)d_in[1];
    const float* W_enc  = (const float*)d_in[2];
    const float* b_enc  = (const float*)d_in[3];
    const float* conv_W = (const float*)d_in[4];
    const float* conv_b = (const float*)d_in[5];
    const float* W_d1   = (const float*)d_in[6];
    const float* b_d1   = (const float*)d_in[7];
    const float* W_d2   = (const float*)d_in[8];
    const float* b_d2   = (const float*)d_in[9];
    const float* W_i1   = (const float*)d_in[10];
    const float* b_i1   = (const float*)d_in[11];
    const float* W_i2   = (const float*)d_in[12];
    const float* b_i2   = (const float*)d_in[13];

    const int N = in_sizes[0] / 5;
    const int E = in_sizes[1] / 2;
    const int NB = (N + NPB - 1) >> NPB_SHIFT;   // <= 256

    float* g    = (float*)d_ws;                           // [N*64] fp32 (ebuf aliases)
    float* hfin = g + (size_t)N * HDIM;                   // [N*64] fp32
    unsigned* hbf = (unsigned*)(hfin + (size_t)N * HDIM); // [N*32] bf16x2
    float* dinv = (float*)(hbf + (size_t)N * 32);
    unsigned* row_ptr = (unsigned*)(dinv + N);            // [N+1]
    unsigned* histT   = row_ptr + N + 1;                  // [NB*PB]
    unsigned* btot    = histT + (size_t)NB * PB;          // [NB]
    int* csr_src      = (int*)(btot + NB);                // [E]
    unsigned* ebuf    = (unsigned*)g;                     // [E] packed (dead before layer 0)
    float* out = (float*)d_out;

    const int hwBlocks = (N + 7) / 8;        // half-wave per node
    const int tnBlocks = (N + 127) / 128;    // 2 threads per node

    // CSR build: bucket sort, no global atomics
    hist_pass<<<PB, 256, 0, stream>>>(ei + E, histT, E, NB);
    scan_bucket<<<NB, 128, 0, stream>>>(histT, btot);
    bin_pass<<<PB, 256, 0, stream>>>(ei, histT, btot, ebuf, E, NB);
    csr_pass<<<NB, 256, 0, stream>>>(ebuf, btot, row_ptr, dinv, csr_src, N, E, NB);

    // encoder -> hn0 (bf16)
    encoder<<<(N * 32 + 255) / 256, 256, 0, stream>>>(x, W_enc, b_enc, dinv, hbf, N);

    // 3 GCN layers
    for (int l = 0; l < 3; l++) {
        gather3<<<hwBlocks, 256, 0, stream>>>(row_ptr, csr_src, hbf, g, N);
        conv_relu<<<tnBlocks, 256, 0, stream>>>(g, conv_W + l * HDIM * HDIM,
                                                conv_b + l * HDIM, dinv, hfin, hbf, N,
                                                (l < 2) ? 1 : 0);
    }

    // heads
    heads2<<<tnBlocks, 256, 0, stream>>>(hfin, W_d1, b_d1, W_d2, b_d2,
                                         W_i1, b_i1, W_i2, b_i2, out, N);
}

// Round 11
// 272.566 us; speedup vs baseline: 1.2782x; 1.0085x over previous
//
#include <hip/hip_runtime.h>
#include <hip/hip_bf16.h>

// SupplyChainGNN: 3-layer GCN, N=50000, E=800000, H=64.
// Round 10: gather software-pipelined -- next batch's 8 indices prefetched
// while current batch's 8 row loads are in flight (round trips per batch
// 2 -> ~1), plus __launch_bounds__(256,6) for 24 waves/CU. Discriminates
// latency-bound vs request-rate-ceiling for the random row reads.
// Rest unchanged from R9 (bucket-sort CSR, bf16x2 hn, broadcast-W conv).

#define HDIM 64
#define PB 128          // blocks in hist/bin passes
#define NPB 256         // nodes per bucket
#define NPB_SHIFT 8

__device__ inline unsigned bfpack(float lo, float hi) {
    unsigned ul = __float_as_uint(lo), uh = __float_as_uint(hi);
    ul += 0x7fffu + ((ul >> 16) & 1u);
    uh += 0x7fffu + ((uh >> 16) & 1u);
    return (ul >> 16) | (uh & 0xffff0000u);
}

__device__ inline float2 bfunpack(unsigned u) {
    float2 r;
    r.x = __uint_as_float(u << 16);
    r.y = __uint_as_float(u & 0xffff0000u);
    return r;
}

// Pass 1: histT[k*PB + p] = #edges of block p with dst in bucket k  (NB<=256)
__global__ __launch_bounds__(256) void hist_pass(const int* __restrict__ dst,
                                                 unsigned* __restrict__ histT,
                                                 int E, int NB) {
    __shared__ unsigned h[256];
    int t = threadIdx.x, p = blockIdx.x;
    h[t] = 0u;
    __syncthreads();
    int chunk = (E + PB - 1) / PB;
    int lo = p * chunk, hi = min(lo + chunk, E);
    for (int e = lo + t; e < hi; e += 256)
        atomicAdd(&h[dst[e] >> NPB_SHIFT], 1u);
    __syncthreads();
    if (t < NB) histT[t * PB + p] = h[t];
}

// Pass 2: per-bucket exclusive scan of its PB per-block counts (in place);
// bucket total -> btot[k].
__global__ __launch_bounds__(128) void scan_bucket(unsigned* __restrict__ histT,
                                                   unsigned* __restrict__ btot) {
    __shared__ unsigned s[PB];
    int t = threadIdx.x, k = blockIdx.x;
    unsigned v = histT[k * PB + t];
    s[t] = v;
    __syncthreads();
#pragma unroll
    for (int off = 1; off < PB; off <<= 1) {
        unsigned u = (t >= off) ? s[t - off] : 0u;
        __syncthreads();
        s[t] += u;
        __syncthreads();
    }
    histT[k * PB + t] = s[t] - v;
    if (t == PB - 1) btot[k] = s[t];
}

// Pass 3: scatter packed (dst_local<<16)|src into bucket-grouped ebuf.
// Each block re-derives bbase via a 256-entry LDS scan of btot.
__global__ __launch_bounds__(256) void bin_pass(const int* __restrict__ ei,
                                                const unsigned* __restrict__ histT,
                                                const unsigned* __restrict__ btot,
                                                unsigned* __restrict__ ebuf,
                                                int E, int NB) {
    __shared__ unsigned bb[256];
    __shared__ unsigned cur[256];
    int t = threadIdx.x, p = blockIdx.x;
    unsigned bv = (t < NB) ? btot[t] : 0u;
    bb[t] = bv;
    __syncthreads();
#pragma unroll
    for (int off = 1; off < 256; off <<= 1) {
        unsigned u = (t >= off) ? bb[t - off] : 0u;
        __syncthreads();
        bb[t] += u;
        __syncthreads();
    }
    if (t < NB) cur[t] = histT[t * PB + p] + (bb[t] - bv);
    __syncthreads();
    int chunk = (E + PB - 1) / PB;
    int lo = p * chunk, hi = min(lo + chunk, E);
    for (int e = lo + t; e < hi; e += 256) {
        unsigned sN = (unsigned)ei[e];
        unsigned dN = (unsigned)ei[E + e];
        unsigned pos = atomicAdd(&cur[dN >> NPB_SHIFT], 1u);
        ebuf[pos] = ((dN & (NPB - 1u)) << 16) | sN;
    }
}

// Pass 4: one block per bucket -> row_ptr, dinv, csr_src.
__global__ __launch_bounds__(256) void csr_pass(const unsigned* __restrict__ ebuf,
                                                const unsigned* __restrict__ btot,
                                                unsigned* __restrict__ row_ptr,
                                                float* __restrict__ dinv,
                                                int* __restrict__ csr_src,
                                                int N, int E, int NB) {
    __shared__ unsigned bb[256];
    __shared__ unsigned cntL[NPB];
    __shared__ unsigned sc[NPB];
    __shared__ unsigned cur[NPB];
    int t = threadIdx.x, k = blockIdx.x;
    unsigned bv = (t < NB) ? btot[t] : 0u;
    bb[t] = bv;
    __syncthreads();
#pragma unroll
    for (int off = 1; off < 256; off <<= 1) {
        unsigned u = (t >= off) ? bb[t - off] : 0u;
        __syncthreads();
        bb[t] += u;
        __syncthreads();
    }
    unsigned e1 = bb[k];
    unsigned e0 = e1 - btot[k];
    int nbase = k << NPB_SHIFT;
    cntL[t] = 0u;
    __syncthreads();
    for (unsigned e = e0 + t; e < e1; e += 256)
        atomicAdd(&cntL[ebuf[e] >> 16], 1u);
    __syncthreads();
    unsigned v = cntL[t];
    sc[t] = v;
    __syncthreads();
#pragma unroll
    for (int off = 1; off < NPB; off <<= 1) {
        unsigned u = (t >= off) ? sc[t - off] : 0u;
        __syncthreads();
        sc[t] += u;
        __syncthreads();
    }
    unsigned pos0 = e0 + sc[t] - v;
    cur[t] = pos0;
    int node = nbase + t;
    if (node < N) {
        row_ptr[node] = pos0;
        dinv[node] = rsqrtf((float)(v + 1u));
    }
    if (k == NB - 1 && t == 0) row_ptr[N] = (unsigned)E;
    __syncthreads();
    for (unsigned e = e0 + t; e < e1; e += 256) {
        unsigned ed = ebuf[e];
        unsigned pos = atomicAdd(&cur[ed >> 16], 1u);
        csr_src[pos] = (int)(ed & 0xffffu);
    }
}

// hn[i] = bf16( dinv[i] * relu(x@W+b) ); thread per feature-pair.
__global__ __launch_bounds__(256) void encoder(const float* __restrict__ x,
                                               const float* __restrict__ W,
                                               const float* __restrict__ b,
                                               const float* __restrict__ dinv,
                                               unsigned* __restrict__ hn, int N) {
    int t = blockIdx.x * 256 + threadIdx.x;
    int i = t >> 5, jp = t & 31;
    if (i >= N) return;
    int j0 = 2 * jp;
    float a0 = b[j0], a1 = b[j0 + 1];
#pragma unroll
    for (int k = 0; k < 5; k++) {
        float xv = x[i * 5 + k];
        a0 = fmaf(xv, W[k * 64 + j0], a0);
        a1 = fmaf(xv, W[k * 64 + j0 + 1], a1);
    }
    float di = dinv[i];
    hn[t] = bfpack(di * fmaxf(a0, 0.0f), di * fmaxf(a1, 0.0f));
}

// Half-wave (32 lanes) per node, software-pipelined: next batch's 8 indices
// are issued while the current batch's 8 row loads are outstanding, so the
// idx->row dependency costs ~1 round trip per batch instead of 2.
// launch_bounds(256,6): 24 waves/CU, VGPR cap 85 (body needs ~50, no spill).
__global__ __launch_bounds__(256, 6) void gather4(const unsigned int* __restrict__ row_ptr,
                                                  const int* __restrict__ csr_src,
                                                  const unsigned* __restrict__ hn,
                                                  float* __restrict__ g, int N) {
    int t = blockIdx.x * 256 + threadIdx.x;
    int i = t >> 5;
    if (i >= N) return;
    int fl = t & 31;
    float2 a0 = bfunpack(hn[(size_t)i * 32 + fl]);  // self term
    float2 a1 = {0.f, 0.f}, a2 = {0.f, 0.f}, a3 = {0.f, 0.f};
    float2 a4 = {0.f, 0.f}, a5 = {0.f, 0.f}, a6 = {0.f, 0.f}, a7 = {0.f, 0.f};
    unsigned e0 = row_ptr[i];
    unsigned cnt = row_ptr[i + 1] - e0;
    const int* idx = csr_src + e0;
    unsigned u = 0;
    if (cnt >= 8) {
        int s0 = idx[0], s1 = idx[1], s2 = idx[2], s3 = idx[3];
        int s4 = idx[4], s5 = idx[5], s6 = idx[6], s7 = idx[7];
        while (true) {
            // issue row loads for the current batch
            unsigned v0 = hn[(size_t)s0 * 32 + fl];
            unsigned v1 = hn[(size_t)s1 * 32 + fl];
            unsigned v2 = hn[(size_t)s2 * 32 + fl];
            unsigned v3 = hn[(size_t)s3 * 32 + fl];
            unsigned v4 = hn[(size_t)s4 * 32 + fl];
            unsigned v5 = hn[(size_t)s5 * 32 + fl];
            unsigned v6 = hn[(size_t)s6 * 32 + fl];
            unsigned v7 = hn[(size_t)s7 * 32 + fl];
            unsigned un = u + 8;
            bool more = (un + 8 <= cnt);
            if (more) {  // prefetch next batch's indices while rows are in flight
                s0 = idx[un + 0]; s1 = idx[un + 1]; s2 = idx[un + 2]; s3 = idx[un + 3];
                s4 = idx[un + 4]; s5 = idx[un + 5]; s6 = idx[un + 6]; s7 = idx[un + 7];
            }
            float2 f0 = bfunpack(v0), f1 = bfunpack(v1), f2 = bfunpack(v2), f3 = bfunpack(v3);
            float2 f4 = bfunpack(v4), f5 = bfunpack(v5), f6 = bfunpack(v6), f7 = bfunpack(v7);
            a0.x += f0.x; a0.y += f0.y;  a1.x += f1.x; a1.y += f1.y;
            a2.x += f2.x; a2.y += f2.y;  a3.x += f3.x; a3.y += f3.y;
            a4.x += f4.x; a4.y += f4.y;  a5.x += f5.x; a5.y += f5.y;
            a6.x += f6.x; a6.y += f6.y;  a7.x += f7.x; a7.y += f7.y;
            u = un;
            if (!more) break;
        }
    }
    if (u < cnt) {  // predicated parallel remainder (1..7 edges)
        unsigned last = cnt - 1;
        int s0 = idx[u];
        int s1 = idx[min(u + 1, last)];
        int s2 = idx[min(u + 2, last)];
        int s3 = idx[min(u + 3, last)];
        int s4 = idx[min(u + 4, last)];
        int s5 = idx[min(u + 5, last)];
        int s6 = idx[min(u + 6, last)];
        int s7 = idx[min(u + 7, last)];
        unsigned v0 = hn[(size_t)s0 * 32 + fl];
        unsigned v1 = hn[(size_t)s1 * 32 + fl];
        unsigned v2 = hn[(size_t)s2 * 32 + fl];
        unsigned v3 = hn[(size_t)s3 * 32 + fl];
        unsigned v4 = hn[(size_t)s4 * 32 + fl];
        unsigned v5 = hn[(size_t)s5 * 32 + fl];
        unsigned v6 = hn[(size_t)s6 * 32 + fl];
        unsigned v7 = hn[(size_t)s7 * 32 + fl];
        float2 f0 = bfunpack(v0), f1 = bfunpack(v1), f2 = bfunpack(v2), f3 = bfunpack(v3);
        float2 f4 = bfunpack(v4), f5 = bfunpack(v5), f6 = bfunpack(v6), f7 = bfunpack(v7);
        a0.x += f0.x;                        a0.y += f0.y;
        a1.x += (u + 1 < cnt) ? f1.x : 0.f;  a1.y += (u + 1 < cnt) ? f1.y : 0.f;
        a2.x += (u + 2 < cnt) ? f2.x : 0.f;  a2.y += (u + 2 < cnt) ? f2.y : 0.f;
        a3.x += (u + 3 < cnt) ? f3.x : 0.f;  a3.y += (u + 3 < cnt) ? f3.y : 0.f;
        a4.x += (u + 4 < cnt) ? f4.x : 0.f;  a4.y += (u + 4 < cnt) ? f4.y : 0.f;
        a5.x += (u + 5 < cnt) ? f5.x : 0.f;  a5.y += (u + 5 < cnt) ? f5.y : 0.f;
        a6.x += (u + 6 < cnt) ? f6.x : 0.f;  a6.y += (u + 6 < cnt) ? f6.y : 0.f;
        a7.x += (u + 7 < cnt) ? f7.x : 0.f;  a7.y += (u + 7 < cnt) ? f7.y : 0.f;
    }
    a0.x += a1.x; a0.y += a1.y;  a2.x += a3.x; a2.y += a3.y;
    a4.x += a5.x; a4.y += a5.y;  a6.x += a7.x; a6.y += a7.y;
    a0.x += a2.x; a0.y += a2.y;  a4.x += a6.x; a4.y += a6.y;
    a0.x += a4.x; a0.y += a4.y;
    float2* g2 = (float2*)g;
    g2[(size_t)i * 32 + fl] = a0;
}

// Thread per (node, output-half). Row of g (fp32) in VGPRs; W^T in LDS
// (wave-uniform broadcast ds_read_b128 -> no LDS BW tax).
// outMode=1: write bf16 hn_next = dinv*relu(...)  (layers 0,1)
// outMode=0: write fp32 h = relu(...)             (layer 2, feeds heads)
__global__ __launch_bounds__(256) void conv_relu(const float* __restrict__ g,
                                                 const float* __restrict__ W,
                                                 const float* __restrict__ b,
                                                 const float* __restrict__ dinv,
                                                 float* __restrict__ houtF,
                                                 unsigned* __restrict__ houtB,
                                                 int N, int outMode) {
    __shared__ float WT[64 * 68];
    int tid = threadIdx.x;
    for (int e = tid; e < 4096; e += 256) {
        int k = e >> 6, j = e & 63;
        WT[j * 68 + k] = W[e];
    }
    __syncthreads();
    int half = tid >> 7;
    int i = blockIdx.x * 128 + (tid & 127);
    if (i >= N) return;
    float4 h[16];
    const float4* g4 = (const float4*)(g + (size_t)i * 64);
#pragma unroll
    for (int q = 0; q < 16; q++) h[q] = g4[q];
    float di = dinv[i];
    float os = outMode ? di : 1.0f;
    int jb = half * 32;
#pragma unroll
    for (int j0 = 0; j0 < 32; j0 += 4) {
        float4 acc = {0.f, 0.f, 0.f, 0.f};
        const float* w0 = &WT[(jb + j0) * 68];
#pragma unroll
        for (int q = 0; q < 16; q++) {
            float4 hv = h[q];
            float4 wa = *(const float4*)(w0 + 0 * 68 + 4 * q);
            float4 wb = *(const float4*)(w0 + 1 * 68 + 4 * q);
            float4 wc = *(const float4*)(w0 + 2 * 68 + 4 * q);
            float4 wd = *(const float4*)(w0 + 3 * 68 + 4 * q);
            acc.x = fmaf(hv.x, wa.x, acc.x); acc.x = fmaf(hv.y, wa.y, acc.x);
            acc.x = fmaf(hv.z, wa.z, acc.x); acc.x = fmaf(hv.w, wa.w, acc.x);
            acc.y = fmaf(hv.x, wb.x, acc.y); acc.y = fmaf(hv.y, wb.y, acc.y);
            acc.y = fmaf(hv.z, wb.z, acc.y); acc.y = fmaf(hv.w, wb.w, acc.y);
            acc.z = fmaf(hv.x, wc.x, acc.z); acc.z = fmaf(hv.y, wc.y, acc.z);
            acc.z = fmaf(hv.z, wc.z, acc.z); acc.z = fmaf(hv.w, wc.w, acc.z);
            acc.w = fmaf(hv.x, wd.x, acc.w); acc.w = fmaf(hv.y, wd.y, acc.w);
            acc.w = fmaf(hv.z, wd.z, acc.w); acc.w = fmaf(hv.w, wd.w, acc.w);
        }
        float4 y;
        y.x = fmaxf(fmaf(di, acc.x, b[jb + j0 + 0]), 0.f) * os;
        y.y = fmaxf(fmaf(di, acc.y, b[jb + j0 + 1]), 0.f) * os;
        y.z = fmaxf(fmaf(di, acc.z, b[jb + j0 + 2]), 0.f) * os;
        y.w = fmaxf(fmaf(di, acc.w, b[jb + j0 + 3]), 0.f) * os;
        if (outMode) {
            uint2 p;
            p.x = bfpack(y.x, y.y);
            p.y = bfpack(y.z, y.w);
            *(uint2*)(houtB + (size_t)i * 32 + ((jb + j0) >> 1)) = p;
        } else {
            *(float4*)(houtF + (size_t)i * 64 + jb + j0) = y;
        }
    }
}

// Thread per (node, head). tid<128 -> demand, tid>=128 -> inventory.
__global__ __launch_bounds__(256) void heads2(const float* __restrict__ h,
                                              const float* __restrict__ W_d1, const float* __restrict__ b_d1,
                                              const float* __restrict__ W_d2, const float* __restrict__ b_d2,
                                              const float* __restrict__ W_i1, const float* __restrict__ b_i1,
                                              const float* __restrict__ W_i2, const float* __restrict__ b_i2,
                                              float* __restrict__ out, int N) {
    __shared__ float WT[2][32 * 68];
    int tid = threadIdx.x;
    for (int e = tid; e < 2048; e += 256) {
        int k = e >> 5, j = e & 31;
        WT[0][j * 68 + k] = W_d1[e];
        WT[1][j * 68 + k] = W_i1[e];
    }
    __syncthreads();
    int head = tid >> 7;
    int i = blockIdx.x * 128 + (tid & 127);
    if (i >= N) return;
    float4 hr[16];
    const float4* h4 = (const float4*)(h + (size_t)i * 64);
#pragma unroll
    for (int q = 0; q < 16; q++) hr[q] = h4[q];
    const float* W1T = WT[head];
    const float* b1 = head ? b_i1 : b_d1;
    const float* W2 = head ? W_i2 : W_d2;
    float o = head ? b_i2[0] : b_d2[0];
#pragma unroll
    for (int j0 = 0; j0 < 32; j0 += 4) {
        float4 acc = {b1[j0], b1[j0 + 1], b1[j0 + 2], b1[j0 + 3]};
        const float* w0 = &W1T[j0 * 68];
#pragma unroll
        for (int q = 0; q < 16; q++) {
            float4 hv = hr[q];
            float4 wa = *(const float4*)(w0 + 0 * 68 + 4 * q);
            float4 wb = *(const float4*)(w0 + 1 * 68 + 4 * q);
            float4 wc = *(const float4*)(w0 + 2 * 68 + 4 * q);
            float4 wd = *(const float4*)(w0 + 3 * 68 + 4 * q);
            acc.x = fmaf(hv.x, wa.x, acc.x); acc.x = fmaf(hv.y, wa.y, acc.x);
            acc.x = fmaf(hv.z, wa.z, acc.x); acc.x = fmaf(hv.w, wa.w, acc.x);
            acc.y = fmaf(hv.x, wb.x, acc.y); acc.y = fmaf(hv.y, wb.y, acc.y);
            acc.y = fmaf(hv.z, wb.z, acc.y); acc.y = fmaf(hv.w, wb.w, acc.y);
            acc.z = fmaf(hv.x, wc.x, acc.z); acc.z = fmaf(hv.y, wc.y, acc.z);
            acc.z = fmaf(hv.z, wc.z, acc.z); acc.z = fmaf(hv.w, wc.w, acc.z);
            acc.w = fmaf(hv.x, wd.x, acc.w); acc.w = fmaf(hv.y, wd.y, acc.w);
            acc.w = fmaf(hv.z, wd.z, acc.w); acc.w = fmaf(hv.w, wd.w, acc.w);
        }
        o = fmaf(fmaxf(acc.x, 0.f), W2[j0 + 0], o);
        o = fmaf(fmaxf(acc.y, 0.f), W2[j0 + 1], o);
        o = fmaf(fmaxf(acc.z, 0.f), W2[j0 + 2], o);
        o = fmaf(fmaxf(acc.w, 0.f), W2[j0 + 3], o);
    }
    out[(size_t)head * N + i] = o;
}

extern "C" void kernel_launch(void* const* d_in, const int* in_sizes, int n_in,
                              void* d_out, int out_size, void* d_ws, size_t ws_size,
                              hipStream_t stream) {
    const float* x      = (const float*)d_in[0];
    const int*   ei     = (const int*)d_in[1];
    const float* W_enc  = (const float*)d_in[2];
    const float* b_enc  = (const float*)d_in[3];
    const float* conv_W = (const float*)d_in[4];
    const float* conv_b = (const float*)d_in[5];
    const float* W_d1   = (const float*)d_in[6];
    const float* b_d1   = (const float*)d_in[7];
    const float* W_d2   = (const float*)d_in[8];
    const float* b_d2   = (const float*)d_in[9];
    const float* W_i1   = (const float*)d_in[10];
    const float* b_i1   = (const float*)d_in[11];
    const float* W_i2   = (const float*)d_in[12];
    const float* b_i2   = (const float*)d_in[13];

    const int N = in_sizes[0] / 5;
    const int E = in_sizes[1] / 2;
    const int NB = (N + NPB - 1) >> NPB_SHIFT;   // <= 256

    float* g    = (float*)d_ws;                           // [N*64] fp32 (ebuf aliases)
    float* hfin = g + (size_t)N * HDIM;                   // [N*64] fp32
    unsigned* hbf = (unsigned*)(hfin + (size_t)N * HDIM); // [N*32] bf16x2
    float* dinv = (float*)(hbf + (size_t)N * 32);
    unsigned* row_ptr = (unsigned*)(dinv + N);            // [N+1]
    unsigned* histT   = row_ptr + N + 1;                  // [NB*PB]
    unsigned* btot    = histT + (size_t)NB * PB;          // [NB]
    int* csr_src      = (int*)(btot + NB);                // [E]
    unsigned* ebuf    = (unsigned*)g;                     // [E] packed (dead before layer 0)
    float* out = (float*)d_out;

    const int hwBlocks = (N + 7) / 8;        // half-wave per node
    const int tnBlocks = (N + 127) / 128;    // 2 threads per node

    // CSR build: bucket sort, no global atomics
    hist_pass<<<PB, 256, 0, stream>>>(ei + E, histT, E, NB);
    scan_bucket<<<NB, 128, 0, stream>>>(histT, btot);
    bin_pass<<<PB, 256, 0, stream>>>(ei, histT, btot, ebuf, E, NB);
    csr_pass<<<NB, 256, 0, stream>>>(ebuf, btot, row_ptr, dinv, csr_src, N, E, NB);

    // encoder -> hn0 (bf16)
    encoder<<<(N * 32 + 255) / 256, 256, 0, stream>>>(x, W_enc, b_enc, dinv, hbf, N);

    // 3 GCN layers
    for (int l = 0; l < 3; l++) {
        gather4<<<hwBlocks, 256, 0, stream>>>(row_ptr, csr_src, hbf, g, N);
        conv_relu<<<tnBlocks, 256, 0, stream>>>(g, conv_W + l * HDIM * HDIM,
                                                conv_b + l * HDIM, dinv, hfin, hbf, N,
                                                (l < 2) ? 1 : 0);
    }

    // heads
    heads2<<<tnBlocks, 256, 0, stream>>>(hfin, W_d1, b_d1, W_d2, b_d2,
                                         W_i1, b_i1, W_i2, b_i2, out, N);
}

// Round 12
// 247.159 us; speedup vs baseline: 1.4096x; 1.1028x over previous
//
#include <hip/hip_runtime.h>
#include <hip/hip_bf16.h>

// SupplyChainGNN: 3-layer GCN, N=50000, E=800000, H=64.
// Round 11: fuse MLP heads into layer-2 conv (conv_heads): y-rows staged in
// LDS, weight-LDS region reused for W_d1/W_i1 after a barrier -> removes the
// hfin 25.6MB round trip and the heads2 dispatch. Gather unchanged (R10):
// it sits at the measured device scattered-access ceiling (~12-13 random
// line-req/ns; R5 byte-halving, R9 VGPR cap, R10 pipelining all neutral).

#define HDIM 64
#define PB 128          // blocks in hist/bin passes
#define NPB 256         // nodes per bucket
#define NPB_SHIFT 8

__device__ inline unsigned bfpack(float lo, float hi) {
    unsigned ul = __float_as_uint(lo), uh = __float_as_uint(hi);
    ul += 0x7fffu + ((ul >> 16) & 1u);
    uh += 0x7fffu + ((uh >> 16) & 1u);
    return (ul >> 16) | (uh & 0xffff0000u);
}

__device__ inline float2 bfunpack(unsigned u) {
    float2 r;
    r.x = __uint_as_float(u << 16);
    r.y = __uint_as_float(u & 0xffff0000u);
    return r;
}

// Pass 1: histT[k*PB + p] = #edges of block p with dst in bucket k  (NB<=256)
__global__ __launch_bounds__(256) void hist_pass(const int* __restrict__ dst,
                                                 unsigned* __restrict__ histT,
                                                 int E, int NB) {
    __shared__ unsigned h[256];
    int t = threadIdx.x, p = blockIdx.x;
    h[t] = 0u;
    __syncthreads();
    int chunk = (E + PB - 1) / PB;
    int lo = p * chunk, hi = min(lo + chunk, E);
    for (int e = lo + t; e < hi; e += 256)
        atomicAdd(&h[dst[e] >> NPB_SHIFT], 1u);
    __syncthreads();
    if (t < NB) histT[t * PB + p] = h[t];
}

// Pass 2: per-bucket exclusive scan of its PB per-block counts (in place);
// bucket total -> btot[k].
__global__ __launch_bounds__(128) void scan_bucket(unsigned* __restrict__ histT,
                                                   unsigned* __restrict__ btot) {
    __shared__ unsigned s[PB];
    int t = threadIdx.x, k = blockIdx.x;
    unsigned v = histT[k * PB + t];
    s[t] = v;
    __syncthreads();
#pragma unroll
    for (int off = 1; off < PB; off <<= 1) {
        unsigned u = (t >= off) ? s[t - off] : 0u;
        __syncthreads();
        s[t] += u;
        __syncthreads();
    }
    histT[k * PB + t] = s[t] - v;
    if (t == PB - 1) btot[k] = s[t];
}

// Pass 3: scatter packed (dst_local<<16)|src into bucket-grouped ebuf.
// Each block re-derives bbase via a 256-entry LDS scan of btot.
__global__ __launch_bounds__(256) void bin_pass(const int* __restrict__ ei,
                                                const unsigned* __restrict__ histT,
                                                const unsigned* __restrict__ btot,
                                                unsigned* __restrict__ ebuf,
                                                int E, int NB) {
    __shared__ unsigned bb[256];
    __shared__ unsigned cur[256];
    int t = threadIdx.x, p = blockIdx.x;
    unsigned bv = (t < NB) ? btot[t] : 0u;
    bb[t] = bv;
    __syncthreads();
#pragma unroll
    for (int off = 1; off < 256; off <<= 1) {
        unsigned u = (t >= off) ? bb[t - off] : 0u;
        __syncthreads();
        bb[t] += u;
        __syncthreads();
    }
    if (t < NB) cur[t] = histT[t * PB + p] + (bb[t] - bv);
    __syncthreads();
    int chunk = (E + PB - 1) / PB;
    int lo = p * chunk, hi = min(lo + chunk, E);
    for (int e = lo + t; e < hi; e += 256) {
        unsigned sN = (unsigned)ei[e];
        unsigned dN = (unsigned)ei[E + e];
        unsigned pos = atomicAdd(&cur[dN >> NPB_SHIFT], 1u);
        ebuf[pos] = ((dN & (NPB - 1u)) << 16) | sN;
    }
}

// Pass 4: one block per bucket -> row_ptr, dinv, csr_src.
__global__ __launch_bounds__(256) void csr_pass(const unsigned* __restrict__ ebuf,
                                                const unsigned* __restrict__ btot,
                                                unsigned* __restrict__ row_ptr,
                                                float* __restrict__ dinv,
                                                int* __restrict__ csr_src,
                                                int N, int E, int NB) {
    __shared__ unsigned bb[256];
    __shared__ unsigned cntL[NPB];
    __shared__ unsigned sc[NPB];
    __shared__ unsigned cur[NPB];
    int t = threadIdx.x, k = blockIdx.x;
    unsigned bv = (t < NB) ? btot[t] : 0u;
    bb[t] = bv;
    __syncthreads();
#pragma unroll
    for (int off = 1; off < 256; off <<= 1) {
        unsigned u = (t >= off) ? bb[t - off] : 0u;
        __syncthreads();
        bb[t] += u;
        __syncthreads();
    }
    unsigned e1 = bb[k];
    unsigned e0 = e1 - btot[k];
    int nbase = k << NPB_SHIFT;
    cntL[t] = 0u;
    __syncthreads();
    for (unsigned e = e0 + t; e < e1; e += 256)
        atomicAdd(&cntL[ebuf[e] >> 16], 1u);
    __syncthreads();
    unsigned v = cntL[t];
    sc[t] = v;
    __syncthreads();
#pragma unroll
    for (int off = 1; off < NPB; off <<= 1) {
        unsigned u = (t >= off) ? sc[t - off] : 0u;
        __syncthreads();
        sc[t] += u;
        __syncthreads();
    }
    unsigned pos0 = e0 + sc[t] - v;
    cur[t] = pos0;
    int node = nbase + t;
    if (node < N) {
        row_ptr[node] = pos0;
        dinv[node] = rsqrtf((float)(v + 1u));
    }
    if (k == NB - 1 && t == 0) row_ptr[N] = (unsigned)E;
    __syncthreads();
    for (unsigned e = e0 + t; e < e1; e += 256) {
        unsigned ed = ebuf[e];
        unsigned pos = atomicAdd(&cur[ed >> 16], 1u);
        csr_src[pos] = (int)(ed & 0xffffu);
    }
}

// hn[i] = bf16( dinv[i] * relu(x@W+b) ); thread per feature-pair.
__global__ __launch_bounds__(256) void encoder(const float* __restrict__ x,
                                               const float* __restrict__ W,
                                               const float* __restrict__ b,
                                               const float* __restrict__ dinv,
                                               unsigned* __restrict__ hn, int N) {
    int t = blockIdx.x * 256 + threadIdx.x;
    int i = t >> 5, jp = t & 31;
    if (i >= N) return;
    int j0 = 2 * jp;
    float a0 = b[j0], a1 = b[j0 + 1];
#pragma unroll
    for (int k = 0; k < 5; k++) {
        float xv = x[i * 5 + k];
        a0 = fmaf(xv, W[k * 64 + j0], a0);
        a1 = fmaf(xv, W[k * 64 + j0 + 1], a1);
    }
    float di = dinv[i];
    hn[t] = bfpack(di * fmaxf(a0, 0.0f), di * fmaxf(a1, 0.0f));
}

// Half-wave (32 lanes) per node, software-pipelined (R10).
__global__ __launch_bounds__(256, 6) void gather4(const unsigned int* __restrict__ row_ptr,
                                                  const int* __restrict__ csr_src,
                                                  const unsigned* __restrict__ hn,
                                                  float* __restrict__ g, int N) {
    int t = blockIdx.x * 256 + threadIdx.x;
    int i = t >> 5;
    if (i >= N) return;
    int fl = t & 31;
    float2 a0 = bfunpack(hn[(size_t)i * 32 + fl]);  // self term
    float2 a1 = {0.f, 0.f}, a2 = {0.f, 0.f}, a3 = {0.f, 0.f};
    float2 a4 = {0.f, 0.f}, a5 = {0.f, 0.f}, a6 = {0.f, 0.f}, a7 = {0.f, 0.f};
    unsigned e0 = row_ptr[i];
    unsigned cnt = row_ptr[i + 1] - e0;
    const int* idx = csr_src + e0;
    unsigned u = 0;
    if (cnt >= 8) {
        int s0 = idx[0], s1 = idx[1], s2 = idx[2], s3 = idx[3];
        int s4 = idx[4], s5 = idx[5], s6 = idx[6], s7 = idx[7];
        while (true) {
            unsigned v0 = hn[(size_t)s0 * 32 + fl];
            unsigned v1 = hn[(size_t)s1 * 32 + fl];
            unsigned v2 = hn[(size_t)s2 * 32 + fl];
            unsigned v3 = hn[(size_t)s3 * 32 + fl];
            unsigned v4 = hn[(size_t)s4 * 32 + fl];
            unsigned v5 = hn[(size_t)s5 * 32 + fl];
            unsigned v6 = hn[(size_t)s6 * 32 + fl];
            unsigned v7 = hn[(size_t)s7 * 32 + fl];
            unsigned un = u + 8;
            bool more = (un + 8 <= cnt);
            if (more) {
                s0 = idx[un + 0]; s1 = idx[un + 1]; s2 = idx[un + 2]; s3 = idx[un + 3];
                s4 = idx[un + 4]; s5 = idx[un + 5]; s6 = idx[un + 6]; s7 = idx[un + 7];
            }
            float2 f0 = bfunpack(v0), f1 = bfunpack(v1), f2 = bfunpack(v2), f3 = bfunpack(v3);
            float2 f4 = bfunpack(v4), f5 = bfunpack(v5), f6 = bfunpack(v6), f7 = bfunpack(v7);
            a0.x += f0.x; a0.y += f0.y;  a1.x += f1.x; a1.y += f1.y;
            a2.x += f2.x; a2.y += f2.y;  a3.x += f3.x; a3.y += f3.y;
            a4.x += f4.x; a4.y += f4.y;  a5.x += f5.x; a5.y += f5.y;
            a6.x += f6.x; a6.y += f6.y;  a7.x += f7.x; a7.y += f7.y;
            u = un;
            if (!more) break;
        }
    }
    if (u < cnt) {  // predicated parallel remainder (1..7 edges)
        unsigned last = cnt - 1;
        int s0 = idx[u];
        int s1 = idx[min(u + 1, last)];
        int s2 = idx[min(u + 2, last)];
        int s3 = idx[min(u + 3, last)];
        int s4 = idx[min(u + 4, last)];
        int s5 = idx[min(u + 5, last)];
        int s6 = idx[min(u + 6, last)];
        int s7 = idx[min(u + 7, last)];
        unsigned v0 = hn[(size_t)s0 * 32 + fl];
        unsigned v1 = hn[(size_t)s1 * 32 + fl];
        unsigned v2 = hn[(size_t)s2 * 32 + fl];
        unsigned v3 = hn[(size_t)s3 * 32 + fl];
        unsigned v4 = hn[(size_t)s4 * 32 + fl];
        unsigned v5 = hn[(size_t)s5 * 32 + fl];
        unsigned v6 = hn[(size_t)s6 * 32 + fl];
        unsigned v7 = hn[(size_t)s7 * 32 + fl];
        float2 f0 = bfunpack(v0), f1 = bfunpack(v1), f2 = bfunpack(v2), f3 = bfunpack(v3);
        float2 f4 = bfunpack(v4), f5 = bfunpack(v5), f6 = bfunpack(v6), f7 = bfunpack(v7);
        a0.x += f0.x;                        a0.y += f0.y;
        a1.x += (u + 1 < cnt) ? f1.x : 0.f;  a1.y += (u + 1 < cnt) ? f1.y : 0.f;
        a2.x += (u + 2 < cnt) ? f2.x : 0.f;  a2.y += (u + 2 < cnt) ? f2.y : 0.f;
        a3.x += (u + 3 < cnt) ? f3.x : 0.f;  a3.y += (u + 3 < cnt) ? f3.y : 0.f;
        a4.x += (u + 4 < cnt) ? f4.x : 0.f;  a4.y += (u + 4 < cnt) ? f4.y : 0.f;
        a5.x += (u + 5 < cnt) ? f5.x : 0.f;  a5.y += (u + 5 < cnt) ? f5.y : 0.f;
        a6.x += (u + 6 < cnt) ? f6.x : 0.f;  a6.y += (u + 6 < cnt) ? f6.y : 0.f;
        a7.x += (u + 7 < cnt) ? f7.x : 0.f;  a7.y += (u + 7 < cnt) ? f7.y : 0.f;
    }
    a0.x += a1.x; a0.y += a1.y;  a2.x += a3.x; a2.y += a3.y;
    a4.x += a5.x; a4.y += a5.y;  a6.x += a7.x; a6.y += a7.y;
    a0.x += a2.x; a0.y += a2.y;  a4.x += a6.x; a4.y += a6.y;
    a0.x += a4.x; a0.y += a4.y;
    float2* g2 = (float2*)g;
    g2[(size_t)i * 32 + fl] = a0;
}

// Layers 0,1: thread per (node, output-half), g row in VGPRs, W^T broadcast
// from LDS; writes bf16 hn_next = dinv*relu(dinv*(g@W)+b).
__global__ __launch_bounds__(256) void conv_relu(const float* __restrict__ g,
                                                 const float* __restrict__ W,
                                                 const float* __restrict__ b,
                                                 const float* __restrict__ dinv,
                                                 unsigned* __restrict__ houtB,
                                                 int N) {
    __shared__ float WT[64 * 68];
    int tid = threadIdx.x;
    for (int e = tid; e < 4096; e += 256) {
        int k = e >> 6, j = e & 63;
        WT[j * 68 + k] = W[e];
    }
    __syncthreads();
    int half = tid >> 7;
    int i = blockIdx.x * 128 + (tid & 127);
    if (i >= N) return;
    float4 h[16];
    const float4* g4 = (const float4*)(g + (size_t)i * 64);
#pragma unroll
    for (int q = 0; q < 16; q++) h[q] = g4[q];
    float di = dinv[i];
    int jb = half * 32;
#pragma unroll
    for (int j0 = 0; j0 < 32; j0 += 4) {
        float4 acc = {0.f, 0.f, 0.f, 0.f};
        const float* w0 = &WT[(jb + j0) * 68];
#pragma unroll
        for (int q = 0; q < 16; q++) {
            float4 hv = h[q];
            float4 wa = *(const float4*)(w0 + 0 * 68 + 4 * q);
            float4 wb = *(const float4*)(w0 + 1 * 68 + 4 * q);
            float4 wc = *(const float4*)(w0 + 2 * 68 + 4 * q);
            float4 wd = *(const float4*)(w0 + 3 * 68 + 4 * q);
            acc.x = fmaf(hv.x, wa.x, acc.x); acc.x = fmaf(hv.y, wa.y, acc.x);
            acc.x = fmaf(hv.z, wa.z, acc.x); acc.x = fmaf(hv.w, wa.w, acc.x);
            acc.y = fmaf(hv.x, wb.x, acc.y); acc.y = fmaf(hv.y, wb.y, acc.y);
            acc.y = fmaf(hv.z, wb.z, acc.y); acc.y = fmaf(hv.w, wb.w, acc.y);
            acc.z = fmaf(hv.x, wc.x, acc.z); acc.z = fmaf(hv.y, wc.y, acc.z);
            acc.z = fmaf(hv.z, wc.z, acc.z); acc.z = fmaf(hv.w, wc.w, acc.z);
            acc.w = fmaf(hv.x, wd.x, acc.w); acc.w = fmaf(hv.y, wd.y, acc.w);
            acc.w = fmaf(hv.z, wd.z, acc.w); acc.w = fmaf(hv.w, wd.w, acc.w);
        }
        float4 y;
        y.x = fmaxf(fmaf(di, acc.x, b[jb + j0 + 0]), 0.f) * di;
        y.y = fmaxf(fmaf(di, acc.y, b[jb + j0 + 1]), 0.f) * di;
        y.z = fmaxf(fmaf(di, acc.z, b[jb + j0 + 2]), 0.f) * di;
        y.w = fmaxf(fmaf(di, acc.w, b[jb + j0 + 3]), 0.f) * di;
        uint2 p;
        p.x = bfpack(y.x, y.y);
        p.y = bfpack(y.z, y.w);
        *(uint2*)(houtB + (size_t)i * 32 + ((jb + j0) >> 1)) = p;
    }
}

// Layer 2 + heads fused: conv phase writes y-rows to LDS (ybuf); the conv-W
// LDS region is then reloaded (barrier-separated alias) with W_d1/W_i1
// transposed; heads phase = heads2's dot products reading rows from LDS.
// Removes the hfin 25.6MB global round trip and the heads2 dispatch.
__global__ __launch_bounds__(256) void conv_heads(const float* __restrict__ g,
                                                  const float* __restrict__ W,
                                                  const float* __restrict__ b,
                                                  const float* __restrict__ dinv,
                                                  const float* __restrict__ W_d1, const float* __restrict__ b_d1,
                                                  const float* __restrict__ W_d2, const float* __restrict__ b_d2,
                                                  const float* __restrict__ W_i1, const float* __restrict__ b_i1,
                                                  const float* __restrict__ W_i2, const float* __restrict__ b_i2,
                                                  float* __restrict__ out, int N) {
    __shared__ float WTa[4352];       // conv W^T (64x68), later heads W1^T (2x 32x68)
    __shared__ float ybuf[128 * 68];  // y rows for this block's 128 nodes
    int tid = threadIdx.x;
    for (int e = tid; e < 4096; e += 256) {
        int k = e >> 6, j = e & 63;
        WTa[j * 68 + k] = W[e];
    }
    __syncthreads();
    int half = tid >> 7;
    int n = tid & 127;
    int i = blockIdx.x * 128 + n;
    int jb = half * 32;
    if (i < N) {
        float4 h[16];
        const float4* g4 = (const float4*)(g + (size_t)i * 64);
#pragma unroll
        for (int q = 0; q < 16; q++) h[q] = g4[q];
        float di = dinv[i];
#pragma unroll
        for (int j0 = 0; j0 < 32; j0 += 4) {
            float4 acc = {0.f, 0.f, 0.f, 0.f};
            const float* w0 = &WTa[(jb + j0) * 68];
#pragma unroll
            for (int q = 0; q < 16; q++) {
                float4 hv = h[q];
                float4 wa = *(const float4*)(w0 + 0 * 68 + 4 * q);
                float4 wb = *(const float4*)(w0 + 1 * 68 + 4 * q);
                float4 wc = *(const float4*)(w0 + 2 * 68 + 4 * q);
                float4 wd = *(const float4*)(w0 + 3 * 68 + 4 * q);
                acc.x = fmaf(hv.x, wa.x, acc.x); acc.x = fmaf(hv.y, wa.y, acc.x);
                acc.x = fmaf(hv.z, wa.z, acc.x); acc.x = fmaf(hv.w, wa.w, acc.x);
                acc.y = fmaf(hv.x, wb.x, acc.y); acc.y = fmaf(hv.y, wb.y, acc.y);
                acc.y = fmaf(hv.z, wb.z, acc.y); acc.y = fmaf(hv.w, wb.w, acc.y);
                acc.z = fmaf(hv.x, wc.x, acc.z); acc.z = fmaf(hv.y, wc.y, acc.z);
                acc.z = fmaf(hv.z, wc.z, acc.z); acc.z = fmaf(hv.w, wc.w, acc.z);
                acc.w = fmaf(hv.x, wd.x, acc.w); acc.w = fmaf(hv.y, wd.y, acc.w);
                acc.w = fmaf(hv.z, wd.z, acc.w); acc.w = fmaf(hv.w, wd.w, acc.w);
            }
            float4 y;
            y.x = fmaxf(fmaf(di, acc.x, b[jb + j0 + 0]), 0.f);
            y.y = fmaxf(fmaf(di, acc.y, b[jb + j0 + 1]), 0.f);
            y.z = fmaxf(fmaf(di, acc.z, b[jb + j0 + 2]), 0.f);
            y.w = fmaxf(fmaf(di, acc.w, b[jb + j0 + 3]), 0.f);
            *(float4*)(&ybuf[n * 68 + jb + j0]) = y;
        }
    }
    __syncthreads();                 // conv reads of WTa done; ybuf complete
    for (int e = tid; e < 2048; e += 256) {   // reload WTa with heads W1^T
        int k = e >> 5, j = e & 31;
        WTa[j * 68 + k] = W_d1[e];
        WTa[2176 + j * 68 + k] = W_i1[e];
    }
    __syncthreads();
    if (i >= N) return;              // safe: all barriers passed
    float4 hr[16];
    const float4* y4 = (const float4*)(&ybuf[n * 68]);
#pragma unroll
    for (int q = 0; q < 16; q++) hr[q] = y4[q];
    int head = half;
    const float* W1T = &WTa[head * 2176];
    const float* b1 = head ? b_i1 : b_d1;
    const float* W2 = head ? W_i2 : W_d2;
    float o = head ? b_i2[0] : b_d2[0];
#pragma unroll
    for (int j0 = 0; j0 < 32; j0 += 4) {
        float4 acc = {b1[j0], b1[j0 + 1], b1[j0 + 2], b1[j0 + 3]};
        const float* w0 = &W1T[j0 * 68];
#pragma unroll
        for (int q = 0; q < 16; q++) {
            float4 hv = hr[q];
            float4 wa = *(const float4*)(w0 + 0 * 68 + 4 * q);
            float4 wb = *(const float4*)(w0 + 1 * 68 + 4 * q);
            float4 wc = *(const float4*)(w0 + 2 * 68 + 4 * q);
            float4 wd = *(const float4*)(w0 + 3 * 68 + 4 * q);
            acc.x = fmaf(hv.x, wa.x, acc.x); acc.x = fmaf(hv.y, wa.y, acc.x);
            acc.x = fmaf(hv.z, wa.z, acc.x); acc.x = fmaf(hv.w, wa.w, acc.x);
            acc.y = fmaf(hv.x, wb.x, acc.y); acc.y = fmaf(hv.y, wb.y, acc.y);
            acc.y = fmaf(hv.z, wb.z, acc.y); acc.y = fmaf(hv.w, wb.w, acc.y);
            acc.z = fmaf(hv.x, wc.x, acc.z); acc.z = fmaf(hv.y, wc.y, acc.z);
            acc.z = fmaf(hv.z, wc.z, acc.z); acc.z = fmaf(hv.w, wc.w, acc.z);
            acc.w = fmaf(hv.x, wd.x, acc.w); acc.w = fmaf(hv.y, wd.y, acc.w);
            acc.w = fmaf(hv.z, wd.z, acc.w); acc.w = fmaf(hv.w, wd.w, acc.w);
        }
        o = fmaf(fmaxf(acc.x, 0.f), W2[j0 + 0], o);
        o = fmaf(fmaxf(acc.y, 0.f), W2[j0 + 1], o);
        o = fmaf(fmaxf(acc.z, 0.f), W2[j0 + 2], o);
        o = fmaf(fmaxf(acc.w, 0.f), W2[j0 + 3], o);
    }
    out[(size_t)head * N + i] = o;
}

extern "C" void kernel_launch(void* const* d_in, const int* in_sizes, int n_in,
                              void* d_out, int out_size, void* d_ws, size_t ws_size,
                              hipStream_t stream) {
    const float* x      = (const float*)d_in[0];
    const int*   ei     = (const int*)d_in[1];
    const float* W_enc  = (const float*)d_in[2];
    const float* b_enc  = (const float*)d_in[3];
    const float* conv_W = (const float*)d_in[4];
    const float* conv_b = (const float*)d_in[5];
    const float* W_d1   = (const float*)d_in[6];
    const float* b_d1   = (const float*)d_in[7];
    const float* W_d2   = (const float*)d_in[8];
    const float* b_d2   = (const float*)d_in[9];
    const float* W_i1   = (const float*)d_in[10];
    const float* b_i1   = (const float*)d_in[11];
    const float* W_i2   = (const float*)d_in[12];
    const float* b_i2   = (const float*)d_in[13];

    const int N = in_sizes[0] / 5;
    const int E = in_sizes[1] / 2;
    const int NB = (N + NPB - 1) >> NPB_SHIFT;   // <= 256

    float* g    = (float*)d_ws;                           // [N*64] fp32 (ebuf aliases)
    unsigned* hbf = (unsigned*)(g + (size_t)N * HDIM);    // [N*32] bf16x2
    float* dinv = (float*)(hbf + (size_t)N * 32);
    unsigned* row_ptr = (unsigned*)(dinv + N);            // [N+1]
    unsigned* histT   = row_ptr + N + 1;                  // [NB*PB]
    unsigned* btot    = histT + (size_t)NB * PB;          // [NB]
    int* csr_src      = (int*)(btot + NB);                // [E]
    unsigned* ebuf    = (unsigned*)g;                     // [E] packed (dead before layer 0)
    float* out = (float*)d_out;

    const int hwBlocks = (N + 7) / 8;        // half-wave per node
    const int tnBlocks = (N + 127) / 128;    // 2 threads per node

    // CSR build: bucket sort, no global atomics
    hist_pass<<<PB, 256, 0, stream>>>(ei + E, histT, E, NB);
    scan_bucket<<<NB, 128, 0, stream>>>(histT, btot);
    bin_pass<<<PB, 256, 0, stream>>>(ei, histT, btot, ebuf, E, NB);
    csr_pass<<<NB, 256, 0, stream>>>(ebuf, btot, row_ptr, dinv, csr_src, N, E, NB);

    // encoder -> hn0 (bf16)
    encoder<<<(N * 32 + 255) / 256, 256, 0, stream>>>(x, W_enc, b_enc, dinv, hbf, N);

    // layers 0,1: gather + conv (bf16 out)
    for (int l = 0; l < 2; l++) {
        gather4<<<hwBlocks, 256, 0, stream>>>(row_ptr, csr_src, hbf, g, N);
        conv_relu<<<tnBlocks, 256, 0, stream>>>(g, conv_W + l * HDIM * HDIM,
                                                conv_b + l * HDIM, dinv, hbf, N);
    }

    // layer 2: gather + fused conv+heads -> out
    gather4<<<hwBlocks, 256, 0, stream>>>(row_ptr, csr_src, hbf, g, N);
    conv_heads<<<tnBlocks, 256, 0, stream>>>(g, conv_W + 2 * HDIM * HDIM,
                                             conv_b + 2 * HDIM, dinv,
                                             W_d1, b_d1, W_d2, b_d2,
                                             W_i1, b_i1, W_i2, b_i2, out, N);
}